// Round 1
// baseline (633.565 us; speedup 1.0000x reference)
//
#include <hip/hip_runtime.h>
#include <math.h>

#define HD 128          // N_HEADS * OUT_FEATS
#define IN_F 256
#define NEG_SLOPE 0.2f

// ---------------- degree histogram ----------------
__global__ void deg_kernel(const int* __restrict__ src, const int* __restrict__ dst,
                           int* __restrict__ out_cnt, int* __restrict__ in_cnt, int E) {
    int e = blockIdx.x * blockDim.x + threadIdx.x;
    if (e < E) {
        atomicAdd(&out_cnt[src[e]], 1);
        atomicAdd(&in_cnt[dst[e]], 1);
    }
}

// ---------------- single-block exclusive scan ----------------
__global__ __launch_bounds__(1024) void scan_kernel(const int* __restrict__ in_cnt,
                                                    int* __restrict__ row_start,
                                                    int* __restrict__ cursor, int n) {
    __shared__ int wsum[16];
    __shared__ int stot;
    int tid = threadIdx.x;
    int lane = tid & 63, wid = tid >> 6;
    int offset = 0;
    for (int base = 0; base < n; base += 1024) {
        int i = base + tid;
        int v = (i < n) ? in_cnt[i] : 0;
        int incl = v;
#pragma unroll
        for (int d = 1; d < 64; d <<= 1) {
            int t = __shfl_up(incl, d);
            if (lane >= d) incl += t;
        }
        if (lane == 63) wsum[wid] = incl;
        __syncthreads();
        if (wid == 0 && lane < 16) {
            int wv = wsum[lane];
            int wincl = wv;
#pragma unroll
            for (int d = 1; d < 16; d <<= 1) {
                int t = __shfl_up(wincl, d);
                if (lane >= d) wincl += t;
            }
            wsum[lane] = wincl - wv;       // exclusive prefix of wave sums
            if (lane == 15) stot = wincl;  // block total
        }
        __syncthreads();
        int excl = offset + wsum[wid] + incl - v;
        if (i < n) { row_start[i] = excl; cursor[i] = excl; }
        offset += stot;
        __syncthreads();  // protect wsum/stot before next iteration
    }
    if (tid == 0) row_start[n] = offset;
}

// ---------------- scatter edges into dst-sorted order ----------------
__global__ void scatter_kernel(const int* __restrict__ src, const int* __restrict__ dst,
                               int* __restrict__ cursor, int* __restrict__ esrc, int E) {
    int e = blockIdx.x * blockDim.x + threadIdx.x;
    if (e < E) {
        int d = dst[e];
        int pos = atomicAdd(&cursor[d], 1);
        esrc[pos] = src[e];
    }
}

// ---------------- tiled GEMM: h_src (normalized) + residual ----------------
#define BM 64
#define KC 32
__global__ __launch_bounds__(256) void gemm_kernel(
    const float* __restrict__ feat, const float* __restrict__ Wfc,
    const float* __restrict__ Wres, const int* __restrict__ out_cnt,
    float* __restrict__ h_src, float* __restrict__ resid, int N) {
    __shared__ float sF[BM][KC + 4];    // stride 36 floats: conflict-safe, 16B-aligned
    __shared__ float sW[256][KC + 4];
    int tid = threadIdx.x;
    int tx = tid & 15;   // col group: owns cols tx + 16*j
    int ty = tid >> 4;   // row group: owns rows ty*4 .. +3
    int bm = blockIdx.x * BM;
    float acc[4][16];
#pragma unroll
    for (int i = 0; i < 4; i++)
#pragma unroll
        for (int j = 0; j < 16; j++) acc[i][j] = 0.f;

    int fr = tid >> 2;           // 0..63
    int fc = (tid & 3) * 8;      // 0,8,16,24
    const float* wrow = (tid < HD) ? (Wfc + (size_t)tid * IN_F)
                                   : (Wres + (size_t)(tid - HD) * IN_F);
    for (int k0 = 0; k0 < IN_F; k0 += KC) {
        int gm = bm + fr;
        float4 a = make_float4(0.f, 0.f, 0.f, 0.f), b = a;
        if (gm < N) {
            a = *(const float4*)(feat + (size_t)gm * IN_F + k0 + fc);
            b = *(const float4*)(feat + (size_t)gm * IN_F + k0 + fc + 4);
        }
        *(float4*)&sF[fr][fc] = a;
        *(float4*)&sF[fr][fc + 4] = b;
#pragma unroll
        for (int q = 0; q < KC / 4; q++)
            *(float4*)&sW[tid][4 * q] = *(const float4*)(wrow + k0 + 4 * q);
        __syncthreads();
#pragma unroll
        for (int k = 0; k < KC; k += 4) {
            float4 f[4];
#pragma unroll
            for (int i = 0; i < 4; i++) f[i] = *(float4*)&sF[ty * 4 + i][k];
#pragma unroll
            for (int jj = 0; jj < 2; jj++) {
                float4 w[8];
#pragma unroll
                for (int j = 0; j < 8; j++) w[j] = *(float4*)&sW[tx + 16 * (jj * 8 + j)][k];
#pragma unroll
                for (int i = 0; i < 4; i++)
#pragma unroll
                    for (int j = 0; j < 8; j++)
                        acc[i][jj * 8 + j] += f[i].x * w[j].x + f[i].y * w[j].y +
                                              f[i].z * w[j].z + f[i].w * w[j].w;
            }
        }
        __syncthreads();
    }
    // epilogue
#pragma unroll
    for (int i = 0; i < 4; i++) {
        int gm = bm + ty * 4 + i;
        if (gm >= N) continue;
        float nrm = rsqrtf(fmaxf((float)out_cnt[gm], 1.0f));
#pragma unroll
        for (int j = 0; j < 16; j++) {
            int col = tx + 16 * j;
            float v = acc[i][j];
            if (col < HD) h_src[(size_t)gm * HD + col] = v * nrm;
            else          resid[(size_t)gm * HD + (col - HD)] = v;
        }
    }
}

// ---------------- per-node attention halves el / er ----------------
__global__ __launch_bounds__(256) void eler_kernel(const float* __restrict__ h_src,
                                                   const float* __restrict__ attn_l,
                                                   const float* __restrict__ attn_r,
                                                   const int* __restrict__ out_cnt,
                                                   float* __restrict__ el,
                                                   float* __restrict__ er, int N) {
    int wid = threadIdx.x >> 6, lane = threadIdx.x & 63;
    int n = blockIdx.x * 4 + wid;
    if (n >= N) return;
    int j0 = lane * 2;
    int h = j0 >> 5;
    float2 hv = *(const float2*)(h_src + (size_t)n * HD + j0);
    float2 al = *(const float2*)(attn_l + j0);
    float2 ar = *(const float2*)(attn_r + j0);
    float pl = hv.x * al.x + hv.y * al.y;
    float pr = hv.x * ar.x + hv.y * ar.y;
#pragma unroll
    for (int m = 1; m < 16; m <<= 1) {
        pl += __shfl_xor(pl, m);
        pr += __shfl_xor(pr, m);
    }
    if ((lane & 15) == 0) {
        el[n * 4 + h] = pl;
        // er uses pre-norm h = h_src / nrm  -> multiply back by sqrt(clip(deg,1))
        er[n * 4 + h] = pr * sqrtf(fmaxf((float)out_cnt[n], 1.0f));
    }
}

// ---------------- fused edge softmax + weighted scatter + final ----------------
__global__ __launch_bounds__(256) void agg_kernel(const float* __restrict__ h_src,
                                                  const float* __restrict__ el,
                                                  const float* __restrict__ er,
                                                  const int* __restrict__ row_start,
                                                  const int* __restrict__ esrc,
                                                  float* __restrict__ out, int N) {
    int wid = threadIdx.x >> 6, lane = threadIdx.x & 63;
    int n = blockIdx.x * 4 + wid;
    if (n >= N) return;
    int j0 = lane * 2;
    int h = j0 >> 5;
    int beg = row_start[n], end = row_start[n + 1];
    float erh = er[n * 4 + h];
    float acc0 = 0.f, acc1 = 0.f, den = 0.f;
    for (int i = beg; i < end; i++) {
        int s = esrc[i];
        float e = el[s * 4 + h] + erh;
        e = (e > 0.f) ? e : NEG_SLOPE * e;
        float ex = __expf(e);
        float2 v = *(const float2*)(h_src + (size_t)s * HD + j0);
        den += ex;
        acc0 += ex * v.x;
        acc1 += ex * v.y;
    }
    float2 res = *(const float2*)(out + (size_t)n * HD + j0);
    float o0 = res.x, o1 = res.y;
    int indeg = end - beg;
    if (indeg > 0) {
        float sc = sqrtf((float)indeg) / den;  // sqrt(clip(in_deg,1)) / denom
        o0 += sc * acc0;
        o1 += sc * acc1;
    }
    *(float2*)(out + (size_t)n * HD + j0) = make_float2(o0, o1);
}

extern "C" void kernel_launch(void* const* d_in, const int* in_sizes, int n_in,
                              void* d_out, int out_size, void* d_ws, size_t ws_size,
                              hipStream_t stream) {
    const float* feat   = (const float*)d_in[0];
    const int*   src    = (const int*)d_in[1];
    const int*   dst    = (const int*)d_in[2];
    const float* W_fc   = (const float*)d_in[3];
    const float* attn_l = (const float*)d_in[4];
    const float* attn_r = (const float*)d_in[5];
    const float* W_res  = (const float*)d_in[6];
    float* out = (float*)d_out;

    int N = in_sizes[0] / IN_F;   // 50000
    int E = in_sizes[1];          // 800000

    // workspace layout
    size_t off = 0;
    auto alloc = [&](size_t bytes) {
        size_t o = off;
        off = (off + bytes + 255) & ~(size_t)255;
        return o;
    };
    char* ws = (char*)d_ws;
    float* h_src    = (float*)(ws + alloc((size_t)N * HD * 4));
    float* el       = (float*)(ws + alloc((size_t)N * 4 * 4));
    float* er       = (float*)(ws + alloc((size_t)N * 4 * 4));
    int* out_cnt    = (int*)(ws + alloc((size_t)N * 4));
    int* in_cnt     = (int*)(ws + alloc((size_t)N * 4));
    int* row_start  = (int*)(ws + alloc((size_t)(N + 1) * 4));
    int* cursor     = (int*)(ws + alloc((size_t)N * 4));
    int* esrc       = (int*)(ws + alloc((size_t)E * 4));
    (void)ws_size;

    hipMemsetAsync(out_cnt, 0, (size_t)N * 4, stream);
    hipMemsetAsync(in_cnt, 0, (size_t)N * 4, stream);

    int eb = (E + 255) / 256;
    deg_kernel<<<eb, 256, 0, stream>>>(src, dst, out_cnt, in_cnt, E);
    scan_kernel<<<1, 1024, 0, stream>>>(in_cnt, row_start, cursor, N);
    scatter_kernel<<<eb, 256, 0, stream>>>(src, dst, cursor, esrc, E);
    gemm_kernel<<<(N + BM - 1) / BM, 256, 0, stream>>>(feat, W_fc, W_res, out_cnt,
                                                       h_src, out, N);
    int nb4 = (N + 3) / 4;
    eler_kernel<<<nb4, 256, 0, stream>>>(h_src, attn_l, attn_r, out_cnt, el, er, N);
    agg_kernel<<<nb4, 256, 0, stream>>>(h_src, el, er, row_start, esrc, out, N);
}

// Round 2
// 280.013 us; speedup vs baseline: 2.2626x; 2.2626x over previous
//
#include <hip/hip_runtime.h>
#include <hip/hip_bf16.h>
#include <math.h>

#define HD 128          // N_HEADS * OUT_FEATS
#define IN_F 256
#define NEG_SLOPE 0.2f

typedef __attribute__((ext_vector_type(8))) short short8;
typedef __attribute__((ext_vector_type(4))) float f32x4;

// ---------------- f32 -> bf16 conversion (feat + both weight mats) ----------------
__global__ void cvt_kernel(const float4* __restrict__ feat, const float4* __restrict__ wfc,
                           const float4* __restrict__ wres, ushort4* __restrict__ feat16,
                           ushort4* __restrict__ w16, int nfeat4, int nw4each) {
    int total = nfeat4 + 2 * nw4each;
    for (int idx = blockIdx.x * blockDim.x + threadIdx.x; idx < total;
         idx += gridDim.x * blockDim.x) {
        float4 f;
        ushort4* o;
        if (idx < nfeat4) { f = feat[idx]; o = feat16 + idx; }
        else if (idx < nfeat4 + nw4each) { f = wfc[idx - nfeat4]; o = w16 + (idx - nfeat4); }
        else { f = wres[idx - nfeat4 - nw4each]; o = w16 + (idx - nfeat4); }
        __hip_bfloat16 bx = __float2bfloat16(f.x);
        __hip_bfloat16 by = __float2bfloat16(f.y);
        __hip_bfloat16 bz = __float2bfloat16(f.z);
        __hip_bfloat16 bw = __float2bfloat16(f.w);
        ushort4 u;
        u.x = *(unsigned short*)&bx; u.y = *(unsigned short*)&by;
        u.z = *(unsigned short*)&bz; u.w = *(unsigned short*)&bw;
        *o = u;
    }
}

// ---------------- degree histogram ----------------
__global__ void deg_kernel(const int* __restrict__ src, const int* __restrict__ dst,
                           int* __restrict__ out_cnt, int* __restrict__ in_cnt, int E) {
    int e = blockIdx.x * blockDim.x + threadIdx.x;
    if (e < E) {
        atomicAdd(&out_cnt[src[e]], 1);
        atomicAdd(&in_cnt[dst[e]], 1);
    }
}

// ---------------- 3-phase parallel scan ----------------
__global__ __launch_bounds__(256) void scan1_kernel(const int* __restrict__ in_cnt,
                                                    int* __restrict__ bsum, int N) {
    __shared__ int wsum[4];
    int i = blockIdx.x * 256 + threadIdx.x;
    int v = (i < N) ? in_cnt[i] : 0;
#pragma unroll
    for (int d = 1; d < 64; d <<= 1) v += __shfl_xor(v, d);
    if ((threadIdx.x & 63) == 0) wsum[threadIdx.x >> 6] = v;
    __syncthreads();
    if (threadIdx.x == 0) bsum[blockIdx.x] = wsum[0] + wsum[1] + wsum[2] + wsum[3];
}

__global__ __launch_bounds__(256) void scan2_kernel(int* __restrict__ bsum, int nb,
                                                    int* __restrict__ row_start_N, int E) {
    __shared__ int wtot[4];
    int tid = threadIdx.x, lane = tid & 63, wid = tid >> 6;
    int v = (tid < nb) ? bsum[tid] : 0;
    int incl = v;
#pragma unroll
    for (int d = 1; d < 64; d <<= 1) {
        int t = __shfl_up(incl, d);
        if (lane >= d) incl += t;
    }
    if (lane == 63) wtot[wid] = incl;
    __syncthreads();
    int woff = 0;
    for (int w = 0; w < wid; w++) woff += wtot[w];
    if (tid < nb) bsum[tid] = woff + incl - v;  // exclusive block offset, in place
    if (tid == 0) *row_start_N = E;             // row_start[N]
}

__global__ __launch_bounds__(256) void scan3_kernel(const int* __restrict__ in_cnt,
                                                    const int* __restrict__ boff,
                                                    int* __restrict__ row_start,
                                                    int* __restrict__ cursor, int N) {
    __shared__ int wsum[4];
    int i = blockIdx.x * 256 + threadIdx.x;
    int lane = threadIdx.x & 63, wid = threadIdx.x >> 6;
    int v = (i < N) ? in_cnt[i] : 0;
    int incl = v;
#pragma unroll
    for (int d = 1; d < 64; d <<= 1) {
        int t = __shfl_up(incl, d);
        if (lane >= d) incl += t;
    }
    if (lane == 63) wsum[wid] = incl;
    __syncthreads();
    int woff = 0;
    for (int w = 0; w < wid; w++) woff += wsum[w];
    int excl = boff[blockIdx.x] + woff + incl - v;
    if (i < N) { row_start[i] = excl; cursor[i] = excl; }
}

// ---------------- scatter edges into dst-sorted order ----------------
__global__ void scatter_kernel(const int* __restrict__ src, const int* __restrict__ dst,
                               int* __restrict__ cursor, int* __restrict__ esrc, int E) {
    int e = blockIdx.x * blockDim.x + threadIdx.x;
    if (e < E) {
        int d = dst[e];
        int pos = atomicAdd(&cursor[d], 1);
        esrc[pos] = src[e];
    }
}

// ---------------- MFMA bf16 GEMM, LDS-free (operands from L2/L3) ----------------
// C[m][c] = sum_k feat[m][k] * Wc[c][k], c<128 -> h_src (normed), c>=128 -> resid(out)
__global__ __launch_bounds__(256) void mfma_gemm(
    const __hip_bfloat16* __restrict__ feat16, const __hip_bfloat16* __restrict__ w16,
    const int* __restrict__ out_cnt, float* __restrict__ h_src,
    float* __restrict__ out, int N) {
    int lane = threadIdx.x & 63, wid = threadIdx.x >> 6;
    int wm = wid >> 1, wn = wid & 1;            // 2x2 wave grid -> 128x128 block tile
    int rowbase = blockIdx.x * 128 + wm * 64;
    int colbase = blockIdx.y * 128 + wn * 64;
    int l15 = lane & 15, lg = lane >> 4;

    f32x4 acc[4][4];
#pragma unroll
    for (int i = 0; i < 4; i++)
#pragma unroll
        for (int j = 0; j < 4; j++) acc[i][j] = (f32x4){0.f, 0.f, 0.f, 0.f};

    const __hip_bfloat16* aptr[4];
    const __hip_bfloat16* bptr[4];
#pragma unroll
    for (int mi = 0; mi < 4; mi++) {
        int r = rowbase + mi * 16 + l15;
        r = (r < N) ? r : (N - 1);              // clamp; garbage rows never stored
        aptr[mi] = feat16 + (size_t)r * IN_F + lg * 8;
    }
#pragma unroll
    for (int ni = 0; ni < 4; ni++) {
        int c = colbase + ni * 16 + l15;        // c < 256 always
        bptr[ni] = w16 + (size_t)c * IN_F + lg * 8;
    }

    for (int k0 = 0; k0 < IN_F; k0 += 32) {
        short8 a[4], b[4];
#pragma unroll
        for (int mi = 0; mi < 4; mi++) a[mi] = *(const short8*)(aptr[mi] + k0);
#pragma unroll
        for (int ni = 0; ni < 4; ni++) b[ni] = *(const short8*)(bptr[ni] + k0);
#pragma unroll
        for (int mi = 0; mi < 4; mi++)
#pragma unroll
            for (int ni = 0; ni < 4; ni++)
                acc[mi][ni] = __builtin_amdgcn_mfma_f32_16x16x32_bf16(
                    a[mi], b[ni], acc[mi][ni], 0, 0, 0);
    }

    // C/D layout (m89): col = lane&15, row = 4*(lane>>4) + reg
    bool isH = (blockIdx.y == 0);
    int colloc = colbase & 127;                  // local col within the 128-wide half
#pragma unroll
    for (int mi = 0; mi < 4; mi++) {
#pragma unroll
        for (int reg = 0; reg < 4; reg++) {
            int r = rowbase + mi * 16 + lg * 4 + reg;
            if (r >= N) continue;
            float scale = isH ? rsqrtf(fmaxf((float)out_cnt[r], 1.0f)) : 1.0f;
            float* dstp = (isH ? h_src : out) + (size_t)r * HD + colloc + l15;
#pragma unroll
            for (int ni = 0; ni < 4; ni++)
                dstp[ni * 16] = acc[mi][ni][reg] * scale;
        }
    }
}

// ---------------- per-node attention halves el / er ----------------
__global__ __launch_bounds__(256) void eler_kernel(const float* __restrict__ h_src,
                                                   const float* __restrict__ attn_l,
                                                   const float* __restrict__ attn_r,
                                                   const int* __restrict__ out_cnt,
                                                   float* __restrict__ el,
                                                   float* __restrict__ er, int N) {
    int wid = threadIdx.x >> 6, lane = threadIdx.x & 63;
    int n = blockIdx.x * 4 + wid;
    if (n >= N) return;
    int j0 = lane * 2;
    int h = j0 >> 5;
    float2 hv = *(const float2*)(h_src + (size_t)n * HD + j0);
    float2 al = *(const float2*)(attn_l + j0);
    float2 ar = *(const float2*)(attn_r + j0);
    float pl = hv.x * al.x + hv.y * al.y;
    float pr = hv.x * ar.x + hv.y * ar.y;
#pragma unroll
    for (int m = 1; m < 16; m <<= 1) {
        pl += __shfl_xor(pl, m);
        pr += __shfl_xor(pr, m);
    }
    if ((lane & 15) == 0) {
        el[n * 4 + h] = pl;
        // er uses pre-norm h -> multiply normalized h_src back by sqrt(clip(deg,1))
        er[n * 4 + h] = pr * sqrtf(fmaxf((float)out_cnt[n], 1.0f));
    }
}

// ---------------- fused edge softmax + weighted scatter + final ----------------
__global__ __launch_bounds__(256) void agg_kernel(const float* __restrict__ h_src,
                                                  const float* __restrict__ el,
                                                  const float* __restrict__ er,
                                                  const int* __restrict__ row_start,
                                                  const int* __restrict__ esrc,
                                                  float* __restrict__ out, int N) {
    int wid = threadIdx.x >> 6, lane = threadIdx.x & 63;
    int n = blockIdx.x * 4 + wid;
    if (n >= N) return;
    int j0 = lane * 2;
    int h = j0 >> 5;
    int beg = row_start[n], end = row_start[n + 1];
    float erh = er[n * 4 + h];
    float acc0 = 0.f, acc1 = 0.f, den = 0.f;
    for (int i = beg; i < end; i++) {
        int s = esrc[i];
        float e = el[s * 4 + h] + erh;
        e = (e > 0.f) ? e : NEG_SLOPE * e;
        float ex = __expf(e);
        float2 v = *(const float2*)(h_src + (size_t)s * HD + j0);
        den += ex;
        acc0 += ex * v.x;
        acc1 += ex * v.y;
    }
    float2 res = *(const float2*)(out + (size_t)n * HD + j0);
    float o0 = res.x, o1 = res.y;
    int indeg = end - beg;
    if (indeg > 0) {
        float sc = sqrtf((float)indeg) / den;  // sqrt(clip(in_deg,1)) / denom
        o0 += sc * acc0;
        o1 += sc * acc1;
    }
    *(float2*)(out + (size_t)n * HD + j0) = make_float2(o0, o1);
}

extern "C" void kernel_launch(void* const* d_in, const int* in_sizes, int n_in,
                              void* d_out, int out_size, void* d_ws, size_t ws_size,
                              hipStream_t stream) {
    const float* feat   = (const float*)d_in[0];
    const int*   src    = (const int*)d_in[1];
    const int*   dst    = (const int*)d_in[2];
    const float* W_fc   = (const float*)d_in[3];
    const float* attn_l = (const float*)d_in[4];
    const float* attn_r = (const float*)d_in[5];
    const float* W_res  = (const float*)d_in[6];
    float* out = (float*)d_out;

    int N = in_sizes[0] / IN_F;   // 50000
    int E = in_sizes[1];          // 800000
    int nb = (N + 255) / 256;     // 196 scan blocks (must be <= 256)

    // workspace layout
    size_t off = 0;
    auto alloc = [&](size_t bytes) {
        size_t o = off;
        off = (off + bytes + 255) & ~(size_t)255;
        return o;
    };
    char* ws = (char*)d_ws;
    float* h_src              = (float*)(ws + alloc((size_t)N * HD * 4));
    __hip_bfloat16* feat16    = (__hip_bfloat16*)(ws + alloc((size_t)N * IN_F * 2));
    __hip_bfloat16* w16       = (__hip_bfloat16*)(ws + alloc((size_t)2 * HD * IN_F * 2));
    float* el                 = (float*)(ws + alloc((size_t)N * 4 * 4));
    float* er                 = (float*)(ws + alloc((size_t)N * 4 * 4));
    int* out_cnt              = (int*)(ws + alloc((size_t)N * 4));
    int* in_cnt               = (int*)(ws + alloc((size_t)N * 4));
    int* row_start            = (int*)(ws + alloc((size_t)(N + 1) * 4));
    int* cursor               = (int*)(ws + alloc((size_t)N * 4));
    int* bsum                 = (int*)(ws + alloc((size_t)nb * 4));
    int* esrc                 = (int*)(ws + alloc((size_t)E * 4));
    (void)ws_size;

    hipMemsetAsync(out_cnt, 0, (size_t)N * 4, stream);
    hipMemsetAsync(in_cnt, 0, (size_t)N * 4, stream);

    int nfeat4 = N * IN_F / 4;
    int nw4each = HD * IN_F / 4;
    cvt_kernel<<<2048, 256, 0, stream>>>((const float4*)feat, (const float4*)W_fc,
                                         (const float4*)W_res, (ushort4*)feat16,
                                         (ushort4*)w16, nfeat4, nw4each);

    int eb = (E + 255) / 256;
    deg_kernel<<<eb, 256, 0, stream>>>(src, dst, out_cnt, in_cnt, E);
    scan1_kernel<<<nb, 256, 0, stream>>>(in_cnt, bsum, N);
    scan2_kernel<<<1, 256, 0, stream>>>(bsum, nb, row_start + N, E);
    scan3_kernel<<<nb, 256, 0, stream>>>(in_cnt, bsum, row_start, cursor, N);
    scatter_kernel<<<eb, 256, 0, stream>>>(src, dst, cursor, esrc, E);

    dim3 ggrid((N + 127) / 128, 2);
    mfma_gemm<<<ggrid, 256, 0, stream>>>(feat16, w16, out_cnt, h_src, out, N);

    int nb4 = (N + 3) / 4;
    eler_kernel<<<nb4, 256, 0, stream>>>(h_src, attn_l, attn_r, out_cnt, el, er, N);
    agg_kernel<<<nb4, 256, 0, stream>>>(h_src, el, er, row_start, esrc, out, N);
}

// Round 3
// 261.741 us; speedup vs baseline: 2.4206x; 1.0698x over previous
//
#include <hip/hip_runtime.h>
#include <hip/hip_bf16.h>
#include <math.h>

#define HD 128          // N_HEADS * OUT_FEATS
#define IN_F 256
#define NEG_SLOPE 0.2f

typedef __attribute__((ext_vector_type(8))) short short8;
typedef __attribute__((ext_vector_type(4))) float f32x4;

__device__ __forceinline__ unsigned short f2bf(float x) {
    __hip_bfloat16 b = __float2bfloat16(x);
    return *(unsigned short*)&b;
}
__device__ __forceinline__ float bf2f(unsigned short u) {
    unsigned int v = ((unsigned int)u) << 16;
    float f;
    __builtin_memcpy(&f, &v, 4);
    return f;
}

// ---------------- weights f32 -> bf16 ----------------
__global__ void cvt_w_kernel(const float4* __restrict__ wfc, const float4* __restrict__ wres,
                             ushort4* __restrict__ w16, int n4each) {
    int idx = blockIdx.x * blockDim.x + threadIdx.x;
    if (idx >= 2 * n4each) return;
    float4 f = (idx < n4each) ? wfc[idx] : wres[idx - n4each];
    ushort4 u;
    u.x = f2bf(f.x); u.y = f2bf(f.y); u.z = f2bf(f.z); u.w = f2bf(f.w);
    w16[idx] = u;
}

// ---------------- degree histogram ----------------
__global__ void deg_kernel(const int* __restrict__ src, const int* __restrict__ dst,
                           int* __restrict__ out_cnt, int* __restrict__ in_cnt, int E) {
    int e = blockIdx.x * blockDim.x + threadIdx.x;
    if (e < E) {
        atomicAdd(&out_cnt[src[e]], 1);
        atomicAdd(&in_cnt[dst[e]], 1);
    }
}

// ---------------- 3-phase parallel scan ----------------
__global__ __launch_bounds__(256) void scan1_kernel(const int* __restrict__ in_cnt,
                                                    int* __restrict__ bsum, int N) {
    __shared__ int wsum[4];
    int i = blockIdx.x * 256 + threadIdx.x;
    int v = (i < N) ? in_cnt[i] : 0;
#pragma unroll
    for (int d = 1; d < 64; d <<= 1) v += __shfl_xor(v, d);
    if ((threadIdx.x & 63) == 0) wsum[threadIdx.x >> 6] = v;
    __syncthreads();
    if (threadIdx.x == 0) bsum[blockIdx.x] = wsum[0] + wsum[1] + wsum[2] + wsum[3];
}

__global__ __launch_bounds__(256) void scan2_kernel(int* __restrict__ bsum, int nb,
                                                    int* __restrict__ row_start_N, int E) {
    __shared__ int wtot[4];
    int tid = threadIdx.x, lane = tid & 63, wid = tid >> 6;
    int v = (tid < nb) ? bsum[tid] : 0;
    int incl = v;
#pragma unroll
    for (int d = 1; d < 64; d <<= 1) {
        int t = __shfl_up(incl, d);
        if (lane >= d) incl += t;
    }
    if (lane == 63) wtot[wid] = incl;
    __syncthreads();
    int woff = 0;
    for (int w = 0; w < wid; w++) woff += wtot[w];
    if (tid < nb) bsum[tid] = woff + incl - v;  // exclusive block offset, in place
    if (tid == 0) *row_start_N = E;             // row_start[N]
}

__global__ __launch_bounds__(256) void scan3_kernel(const int* __restrict__ in_cnt,
                                                    const int* __restrict__ boff,
                                                    int* __restrict__ row_start,
                                                    int* __restrict__ cursor, int N) {
    __shared__ int wsum[4];
    int i = blockIdx.x * 256 + threadIdx.x;
    int lane = threadIdx.x & 63, wid = threadIdx.x >> 6;
    int v = (i < N) ? in_cnt[i] : 0;
    int incl = v;
#pragma unroll
    for (int d = 1; d < 64; d <<= 1) {
        int t = __shfl_up(incl, d);
        if (lane >= d) incl += t;
    }
    if (lane == 63) wsum[wid] = incl;
    __syncthreads();
    int woff = 0;
    for (int w = 0; w < wid; w++) woff += wsum[w];
    int excl = boff[blockIdx.x] + woff + incl - v;
    if (i < N) { row_start[i] = excl; cursor[i] = excl; }
}

// ---------------- scatter edges into dst-sorted order ----------------
__global__ void scatter_kernel(const int* __restrict__ src, const int* __restrict__ dst,
                               int* __restrict__ cursor, int* __restrict__ esrc, int E) {
    int e = blockIdx.x * blockDim.x + threadIdx.x;
    if (e < E) {
        int d = dst[e];
        int pos = atomicAdd(&cursor[d], 1);
        esrc[pos] = src[e];
    }
}

// ---------------- fused GEMM: cvt(A)->LDS, MFMA, epilogue norm + el/er ----------------
// Block: 128 rows x 256 cols, 8 waves (2 row panels x 4 col panels).
// cols 0..127 -> h16 (normalized, bf16) + el/er; cols 128..255 -> resid into out.
__global__ __launch_bounds__(512) void gemm_fused(
    const float* __restrict__ feat, const __hip_bfloat16* __restrict__ w16,
    const int* __restrict__ out_cnt, const float* __restrict__ attn_l,
    const float* __restrict__ attn_r, unsigned short* __restrict__ h16,
    float* __restrict__ el, float* __restrict__ er, float* __restrict__ out, int N) {
    __shared__ unsigned short sA[128 * 256];  // 64 KiB, XOR-swizzled 16B granules
    int tid = threadIdx.x;
    int lane = tid & 63, wid = tid >> 6;
    int wm = wid >> 2, wn = wid & 3;
    int bm = blockIdx.x * 128;
    int l15 = lane & 15, lg = lane >> 4;

    // ---- stage A: f32 -> bf16 into LDS ----
#pragma unroll
    for (int i = 0; i < 8; i++) {
        int G = i * 512 + tid;          // granule id: 128 rows x 32 granules
        int row = G >> 5, gc = G & 31;
        int gm = bm + row;
        gm = (gm < N) ? gm : (N - 1);
        const float4* fp = (const float4*)(feat + (size_t)gm * IN_F + gc * 8);
        float4 f0 = fp[0], f1 = fp[1];
        short8 v;
        v[0] = (short)f2bf(f0.x); v[1] = (short)f2bf(f0.y);
        v[2] = (short)f2bf(f0.z); v[3] = (short)f2bf(f0.w);
        v[4] = (short)f2bf(f1.x); v[5] = (short)f2bf(f1.y);
        v[6] = (short)f2bf(f1.z); v[7] = (short)f2bf(f1.w);
        *(short8*)&sA[row * 256 + ((gc ^ (row & 7)) * 8)] = v;
    }
    __syncthreads();

    int rowb = wm * 64;
    int colbase = wn * 64;
    const __hip_bfloat16* bp[4];
#pragma unroll
    for (int ni = 0; ni < 4; ni++) {
        int c = colbase + ni * 16 + l15;  // 0..255
        bp[ni] = w16 + (size_t)c * IN_F + lg * 8;
    }

    f32x4 acc[4][4];
#pragma unroll
    for (int i = 0; i < 4; i++)
#pragma unroll
        for (int j = 0; j < 4; j++) acc[i][j] = (f32x4){0.f, 0.f, 0.f, 0.f};

#pragma unroll
    for (int k0 = 0; k0 < IN_F; k0 += 32) {
        short8 a[4], b[4];
#pragma unroll
        for (int mi = 0; mi < 4; mi++) {
            int row = rowb + mi * 16 + l15;
            int gs = ((k0 >> 3) + lg) ^ (row & 7);
            a[mi] = *(const short8*)&sA[row * 256 + gs * 8];
        }
#pragma unroll
        for (int ni = 0; ni < 4; ni++) b[ni] = *(const short8*)(bp[ni] + k0);
#pragma unroll
        for (int mi = 0; mi < 4; mi++)
#pragma unroll
            for (int ni = 0; ni < 4; ni++)
                acc[mi][ni] = __builtin_amdgcn_mfma_f32_16x16x32_bf16(
                    a[mi], b[ni], acc[mi][ni], 0, 0, 0);
    }

    // ---- epilogue. C/D layout: col = lane&15, row = 4*(lane>>4)+reg ----
    bool isH = (wn < 2);
    int colloc = colbase & 127;  // 0 or 64 within each half
    float alv[4], arv[4];
    if (isH) {
#pragma unroll
        for (int ni = 0; ni < 4; ni++) {
            int c = colbase + ni * 16 + l15;  // < 128; flat [H][32] == col index
            alv[ni] = attn_l[c];
            arv[ni] = attn_r[c];
        }
    }
#pragma unroll
    for (int mi = 0; mi < 4; mi++) {
#pragma unroll
        for (int reg = 0; reg < 4; reg++) {
            int r = bm + rowb + mi * 16 + lg * 4 + reg;
            bool valid = (r < N);
            int rr = valid ? r : 0;
            if (isH) {
                float nrm = rsqrtf(fmaxf((float)out_cnt[rr], 1.0f));
                float pl0 = 0.f, pl1 = 0.f, pr0 = 0.f, pr1 = 0.f;
#pragma unroll
                for (int ni = 0; ni < 4; ni++) {
                    float v = acc[mi][ni][reg];
                    if (valid)
                        h16[(size_t)r * HD + colloc + ni * 16 + l15] = f2bf(v * nrm);
                    if (ni < 2) { pl0 += v * alv[ni]; pr0 += v * arv[ni]; }
                    else        { pl1 += v * alv[ni]; pr1 += v * arv[ni]; }
                }
                pl0 *= nrm; pl1 *= nrm;  // el uses normalized h; er uses pre-norm h
#pragma unroll
                for (int m = 1; m < 16; m <<= 1) {
                    pl0 += __shfl_xor(pl0, m); pl1 += __shfl_xor(pl1, m);
                    pr0 += __shfl_xor(pr0, m); pr1 += __shfl_xor(pr1, m);
                }
                if (valid && (lane & 15) == 0) {
                    int hb = wn * 2;  // heads hb, hb+1
                    el[r * 4 + hb] = pl0;     el[r * 4 + hb + 1] = pl1;
                    er[r * 4 + hb] = pr0;     er[r * 4 + hb + 1] = pr1;
                }
            } else if (valid) {
#pragma unroll
                for (int ni = 0; ni < 4; ni++)
                    out[(size_t)r * HD + colloc + ni * 16 + l15] = acc[mi][ni][reg];
            }
        }
    }
}

// ---------------- fused edge softmax + weighted scatter + final ----------------
__global__ __launch_bounds__(256) void agg_kernel(const unsigned short* __restrict__ h16,
                                                  const float* __restrict__ el,
                                                  const float* __restrict__ er,
                                                  const int* __restrict__ row_start,
                                                  const int* __restrict__ esrc,
                                                  float* __restrict__ out, int N) {
    int wid = threadIdx.x >> 6, lane = threadIdx.x & 63;
    int n = blockIdx.x * 4 + wid;
    if (n >= N) return;
    int j0 = lane * 2;
    int h = j0 >> 5;
    int beg = row_start[n], end = row_start[n + 1];
    float erh = er[n * 4 + h];
    float acc0 = 0.f, acc1 = 0.f, den = 0.f;
    for (int i = beg; i < end; i++) {
        int s = esrc[i];
        float e = el[s * 4 + h] + erh;
        e = (e > 0.f) ? e : NEG_SLOPE * e;
        float ex = __expf(e);
        ushort2 v = *(const ushort2*)(h16 + (size_t)s * HD + j0);
        den += ex;
        acc0 += ex * bf2f(v.x);
        acc1 += ex * bf2f(v.y);
    }
    float2 res = *(const float2*)(out + (size_t)n * HD + j0);
    float o0 = res.x, o1 = res.y;
    int indeg = end - beg;
    if (indeg > 0) {
        float sc = sqrtf((float)indeg) / den;  // sqrt(clip(in_deg,1)) / denom
        o0 += sc * acc0;
        o1 += sc * acc1;
    }
    *(float2*)(out + (size_t)n * HD + j0) = make_float2(o0, o1);
}

extern "C" void kernel_launch(void* const* d_in, const int* in_sizes, int n_in,
                              void* d_out, int out_size, void* d_ws, size_t ws_size,
                              hipStream_t stream) {
    const float* feat   = (const float*)d_in[0];
    const int*   src    = (const int*)d_in[1];
    const int*   dst    = (const int*)d_in[2];
    const float* W_fc   = (const float*)d_in[3];
    const float* attn_l = (const float*)d_in[4];
    const float* attn_r = (const float*)d_in[5];
    const float* W_res  = (const float*)d_in[6];
    float* out = (float*)d_out;

    int N = in_sizes[0] / IN_F;   // 50000
    int E = in_sizes[1];          // 800000
    int nb = (N + 255) / 256;     // 196 (<= 256 for scan2)

    size_t off = 0;
    auto alloc = [&](size_t bytes) {
        size_t o = off;
        off = (off + bytes + 255) & ~(size_t)255;
        return o;
    };
    char* ws = (char*)d_ws;
    unsigned short* h16 = (unsigned short*)(ws + alloc((size_t)N * HD * 2));
    __hip_bfloat16* w16 = (__hip_bfloat16*)(ws + alloc((size_t)2 * HD * IN_F * 2));
    float* el           = (float*)(ws + alloc((size_t)N * 4 * 4));
    float* er           = (float*)(ws + alloc((size_t)N * 4 * 4));
    int* out_cnt        = (int*)(ws + alloc((size_t)N * 4));
    int* in_cnt         = (int*)(ws + alloc((size_t)N * 4));
    int* row_start      = (int*)(ws + alloc((size_t)(N + 1) * 4));
    int* cursor         = (int*)(ws + alloc((size_t)N * 4));
    int* bsum           = (int*)(ws + alloc((size_t)nb * 4));
    int* esrc           = (int*)(ws + alloc((size_t)E * 4));
    (void)ws_size;

    hipMemsetAsync(out_cnt, 0, (size_t)N * 4, stream);
    hipMemsetAsync(in_cnt, 0, (size_t)N * 4, stream);

    int n4each = HD * IN_F / 4;
    cvt_w_kernel<<<(2 * n4each + 255) / 256, 256, 0, stream>>>(
        (const float4*)W_fc, (const float4*)W_res, (ushort4*)w16, n4each);

    int eb = (E + 255) / 256;
    deg_kernel<<<eb, 256, 0, stream>>>(src, dst, out_cnt, in_cnt, E);
    scan1_kernel<<<nb, 256, 0, stream>>>(in_cnt, bsum, N);
    scan2_kernel<<<1, 256, 0, stream>>>(bsum, nb, row_start + N, E);
    scan3_kernel<<<nb, 256, 0, stream>>>(in_cnt, bsum, row_start, cursor, N);
    scatter_kernel<<<eb, 256, 0, stream>>>(src, dst, cursor, esrc, E);

    gemm_fused<<<(N + 127) / 128, 512, 0, stream>>>(feat, (const __hip_bfloat16*)w16,
                                                    out_cnt, attn_l, attn_r,
                                                    h16, el, er, out, N);

    int nb4 = (N + 3) / 4;
    agg_kernel<<<nb4, 256, 0, stream>>>(h16, el, er, row_start, esrc, out, N);
}

// Round 4
// 223.120 us; speedup vs baseline: 2.8396x; 1.1731x over previous
//
#include <hip/hip_runtime.h>
#include <hip/hip_bf16.h>
#include <math.h>

#define HD 128          // N_HEADS * OUT_FEATS
#define IN_F 256
#define NEG_SLOPE 0.2f

typedef __attribute__((ext_vector_type(8))) short short8;
typedef __attribute__((ext_vector_type(4))) float f32x4;

__device__ __forceinline__ unsigned short f2bf(float x) {
    __hip_bfloat16 b = __float2bfloat16(x);
    return *(unsigned short*)&b;
}
__device__ __forceinline__ float bf2f(unsigned short u) {
    unsigned int v = ((unsigned int)u) << 16;
    float f;
    __builtin_memcpy(&f, &v, 4);
    return f;
}

// ---------------- weights f32 -> bf16 ----------------
__global__ void cvt_w_kernel(const float4* __restrict__ wfc, const float4* __restrict__ wres,
                             ushort4* __restrict__ w16, int n4each) {
    int idx = blockIdx.x * blockDim.x + threadIdx.x;
    if (idx >= 2 * n4each) return;
    float4 f = (idx < n4each) ? wfc[idx] : wres[idx - n4each];
    ushort4 u;
    u.x = f2bf(f.x); u.y = f2bf(f.y); u.z = f2bf(f.z); u.w = f2bf(f.w);
    w16[idx] = u;
}

// ---------------- degree histogram ----------------
__global__ void deg_kernel(const int* __restrict__ src, const int* __restrict__ dst,
                           int* __restrict__ out_cnt, int* __restrict__ in_cnt, int E) {
    int e = blockIdx.x * blockDim.x + threadIdx.x;
    if (e < E) {
        atomicAdd(&out_cnt[src[e]], 1);
        atomicAdd(&in_cnt[dst[e]], 1);
    }
}

// ---------------- 3-phase parallel scan ----------------
__global__ __launch_bounds__(256) void scan1_kernel(const int* __restrict__ in_cnt,
                                                    int* __restrict__ bsum, int N) {
    __shared__ int wsum[4];
    int i = blockIdx.x * 256 + threadIdx.x;
    int v = (i < N) ? in_cnt[i] : 0;
#pragma unroll
    for (int d = 1; d < 64; d <<= 1) v += __shfl_xor(v, d);
    if ((threadIdx.x & 63) == 0) wsum[threadIdx.x >> 6] = v;
    __syncthreads();
    if (threadIdx.x == 0) bsum[blockIdx.x] = wsum[0] + wsum[1] + wsum[2] + wsum[3];
}

__global__ __launch_bounds__(256) void scan2_kernel(int* __restrict__ bsum, int nb,
                                                    int* __restrict__ row_start_N, int E) {
    __shared__ int wtot[4];
    int tid = threadIdx.x, lane = tid & 63, wid = tid >> 6;
    int v = (tid < nb) ? bsum[tid] : 0;
    int incl = v;
#pragma unroll
    for (int d = 1; d < 64; d <<= 1) {
        int t = __shfl_up(incl, d);
        if (lane >= d) incl += t;
    }
    if (lane == 63) wtot[wid] = incl;
    __syncthreads();
    int woff = 0;
    for (int w = 0; w < wid; w++) woff += wtot[w];
    if (tid < nb) bsum[tid] = woff + incl - v;  // exclusive block offset, in place
    if (tid == 0) *row_start_N = E;             // row_start[N]
}

__global__ __launch_bounds__(256) void scan3_kernel(const int* __restrict__ in_cnt,
                                                    const int* __restrict__ boff,
                                                    int* __restrict__ row_start,
                                                    int* __restrict__ cursor, int N) {
    __shared__ int wsum[4];
    int i = blockIdx.x * 256 + threadIdx.x;
    int lane = threadIdx.x & 63, wid = threadIdx.x >> 6;
    int v = (i < N) ? in_cnt[i] : 0;
    int incl = v;
#pragma unroll
    for (int d = 1; d < 64; d <<= 1) {
        int t = __shfl_up(incl, d);
        if (lane >= d) incl += t;
    }
    if (lane == 63) wsum[wid] = incl;
    __syncthreads();
    int woff = 0;
    for (int w = 0; w < wid; w++) woff += wsum[w];
    int excl = boff[blockIdx.x] + woff + incl - v;
    if (i < N) { row_start[i] = excl; cursor[i] = excl; }
}

// ---------------- scatter edges into dst-sorted order ----------------
__global__ void scatter_kernel(const int* __restrict__ src, const int* __restrict__ dst,
                               int* __restrict__ cursor, int* __restrict__ esrc, int E) {
    int e = blockIdx.x * blockDim.x + threadIdx.x;
    if (e < E) {
        int d = dst[e];
        int pos = atomicAdd(&cursor[d], 1);
        esrc[pos] = src[e];
    }
}

// ---------------- fused GEMM: cvt(A)->LDS, MFMA, epilogue norm + el/er ----------------
// Block: 64 rows x 256 cols, 4 waves (1x4 col panels), 32 KiB LDS.
// cols 0..127 -> h16 (normalized, bf16) + el/er; cols 128..255 -> resid into out.
__global__ __launch_bounds__(256) void gemm_fused(
    const float* __restrict__ feat, const __hip_bfloat16* __restrict__ w16,
    const int* __restrict__ out_cnt, const float* __restrict__ attn_l,
    const float* __restrict__ attn_r, unsigned short* __restrict__ h16,
    float* __restrict__ el, float* __restrict__ er, float* __restrict__ out, int N) {
    __shared__ unsigned short sA[64 * 256];  // 32 KiB, XOR-swizzled 16B granules
    int tid = threadIdx.x;
    int lane = tid & 63, wid = tid >> 6;
    int wn = wid;                 // 4 col panels of 64
    int bm = blockIdx.x * 64;
    int l15 = lane & 15, lg = lane >> 4;

    // ---- stage A: f32 -> bf16 into LDS (64 rows x 32 granules) ----
#pragma unroll
    for (int i = 0; i < 8; i++) {
        int G = i * 256 + tid;          // granule id
        int row = G >> 5, gc = G & 31;
        int gm = bm + row;
        gm = (gm < N) ? gm : (N - 1);
        const float4* fp = (const float4*)(feat + (size_t)gm * IN_F + gc * 8);
        float4 f0 = fp[0], f1 = fp[1];
        short8 v;
        v[0] = (short)f2bf(f0.x); v[1] = (short)f2bf(f0.y);
        v[2] = (short)f2bf(f0.z); v[3] = (short)f2bf(f0.w);
        v[4] = (short)f2bf(f1.x); v[5] = (short)f2bf(f1.y);
        v[6] = (short)f2bf(f1.z); v[7] = (short)f2bf(f1.w);
        *(short8*)&sA[row * 256 + ((gc ^ (row & 7)) * 8)] = v;
    }
    __syncthreads();

    int colbase = wn * 64;
    const __hip_bfloat16* bp[4];
#pragma unroll
    for (int ni = 0; ni < 4; ni++) {
        int c = colbase + ni * 16 + l15;  // 0..255
        bp[ni] = w16 + (size_t)c * IN_F + lg * 8;
    }

    f32x4 acc[4][4];
#pragma unroll
    for (int i = 0; i < 4; i++)
#pragma unroll
        for (int j = 0; j < 4; j++) acc[i][j] = (f32x4){0.f, 0.f, 0.f, 0.f};

#pragma unroll
    for (int k0 = 0; k0 < IN_F; k0 += 32) {
        short8 a[4], b[4];
#pragma unroll
        for (int mi = 0; mi < 4; mi++) {
            int row = mi * 16 + l15;
            int gs = ((k0 >> 3) + lg) ^ (row & 7);
            a[mi] = *(const short8*)&sA[row * 256 + gs * 8];
        }
#pragma unroll
        for (int ni = 0; ni < 4; ni++) b[ni] = *(const short8*)(bp[ni] + k0);
#pragma unroll
        for (int mi = 0; mi < 4; mi++)
#pragma unroll
            for (int ni = 0; ni < 4; ni++)
                acc[mi][ni] = __builtin_amdgcn_mfma_f32_16x16x32_bf16(
                    a[mi], b[ni], acc[mi][ni], 0, 0, 0);
    }

    // ---- epilogue. C/D layout: col = lane&15, row = 4*(lane>>4)+reg ----
    bool isH = (wn < 2);
    int colloc = colbase & 127;  // 0 or 64 within each half
    float alv[4], arv[4];
    if (isH) {
#pragma unroll
        for (int ni = 0; ni < 4; ni++) {
            int c = colbase + ni * 16 + l15;  // < 128; flat [H][32] == col index
            alv[ni] = attn_l[c];
            arv[ni] = attn_r[c];
        }
    }
#pragma unroll
    for (int mi = 0; mi < 4; mi++) {
#pragma unroll
        for (int reg = 0; reg < 4; reg++) {
            int r = bm + mi * 16 + lg * 4 + reg;
            bool valid = (r < N);
            int rr = valid ? r : 0;
            if (isH) {
                float nrm = rsqrtf(fmaxf((float)out_cnt[rr], 1.0f));
                float pl0 = 0.f, pl1 = 0.f, pr0 = 0.f, pr1 = 0.f;
#pragma unroll
                for (int ni = 0; ni < 4; ni++) {
                    float v = acc[mi][ni][reg];
                    if (valid)
                        h16[(size_t)r * HD + colloc + ni * 16 + l15] = f2bf(v * nrm);
                    if (ni < 2) { pl0 += v * alv[ni]; pr0 += v * arv[ni]; }
                    else        { pl1 += v * alv[ni]; pr1 += v * arv[ni]; }
                }
                pl0 *= nrm; pl1 *= nrm;  // el uses normalized h; er uses pre-norm h
#pragma unroll
                for (int m = 1; m < 16; m <<= 1) {
                    pl0 += __shfl_xor(pl0, m); pl1 += __shfl_xor(pl1, m);
                    pr0 += __shfl_xor(pr0, m); pr1 += __shfl_xor(pr1, m);
                }
                if (valid && (lane & 15) == 0) {
                    int hb = wn * 2;  // heads hb, hb+1
                    el[r * 4 + hb] = pl0;     el[r * 4 + hb + 1] = pl1;
                    er[r * 4 + hb] = pr0;     er[r * 4 + hb + 1] = pr1;
                }
            } else if (valid) {
#pragma unroll
                for (int ni = 0; ni < 4; ni++)
                    out[(size_t)r * HD + colloc + ni * 16 + l15] = acc[mi][ni][reg];
            }
        }
    }
}

// ---------------- fused edge softmax + weighted scatter + final ----------------
// One wave per dst node; 8-wide masked chunks for memory-level parallelism.
#define AGG_U 8
__global__ __launch_bounds__(256) void agg_kernel(const unsigned short* __restrict__ h16,
                                                  const float* __restrict__ el,
                                                  const float* __restrict__ er,
                                                  const int* __restrict__ row_start,
                                                  const int* __restrict__ esrc,
                                                  float* __restrict__ out, int N) {
    int wid = threadIdx.x >> 6, lane = threadIdx.x & 63;
    int n = blockIdx.x * 4 + wid;
    if (n >= N) return;
    int j0 = lane * 2;
    int h = lane >> 4;
    int beg = row_start[n], end = row_start[n + 1];
    float erh = er[n * 4 + h];
    float acc0 = 0.f, acc1 = 0.f, den = 0.f;
    for (int i = beg; i < end; i += AGG_U) {
        int s[AGG_U];
        bool ok[AGG_U];
#pragma unroll
        for (int u = 0; u < AGG_U; u++) {
            int idx = i + u;
            ok[u] = idx < end;
            s[u] = esrc[ok[u] ? idx : beg];
        }
        float ev[AGG_U];
        ushort2 v[AGG_U];
#pragma unroll
        for (int u = 0; u < AGG_U; u++) {
            ev[u] = el[s[u] * 4 + h];
            v[u] = *(const ushort2*)(h16 + (size_t)s[u] * HD + j0);
        }
#pragma unroll
        for (int u = 0; u < AGG_U; u++) {
            float e = ev[u] + erh;
            e = (e > 0.f) ? e : NEG_SLOPE * e;
            float ex = ok[u] ? __expf(e) : 0.f;
            den += ex;
            acc0 += ex * bf2f(v[u].x);
            acc1 += ex * bf2f(v[u].y);
        }
    }
    float2 res = *(const float2*)(out + (size_t)n * HD + j0);
    float o0 = res.x, o1 = res.y;
    int indeg = end - beg;
    if (indeg > 0) {
        float sc = sqrtf((float)indeg) / den;  // sqrt(clip(in_deg,1)) / denom
        o0 += sc * acc0;
        o1 += sc * acc1;
    }
    *(float2*)(out + (size_t)n * HD + j0) = make_float2(o0, o1);
}

extern "C" void kernel_launch(void* const* d_in, const int* in_sizes, int n_in,
                              void* d_out, int out_size, void* d_ws, size_t ws_size,
                              hipStream_t stream) {
    const float* feat   = (const float*)d_in[0];
    const int*   src    = (const int*)d_in[1];
    const int*   dst    = (const int*)d_in[2];
    const float* W_fc   = (const float*)d_in[3];
    const float* attn_l = (const float*)d_in[4];
    const float* attn_r = (const float*)d_in[5];
    const float* W_res  = (const float*)d_in[6];
    float* out = (float*)d_out;

    int N = in_sizes[0] / IN_F;   // 50000
    int E = in_sizes[1];          // 800000
    int nb = (N + 255) / 256;     // 196 (<= 256 for scan2)

    size_t off = 0;
    auto alloc = [&](size_t bytes) {
        size_t o = off;
        off = (off + bytes + 255) & ~(size_t)255;
        return o;
    };
    char* ws = (char*)d_ws;
    unsigned short* h16 = (unsigned short*)(ws + alloc((size_t)N * HD * 2));
    __hip_bfloat16* w16 = (__hip_bfloat16*)(ws + alloc((size_t)2 * HD * IN_F * 2));
    float* el           = (float*)(ws + alloc((size_t)N * 4 * 4));
    float* er           = (float*)(ws + alloc((size_t)N * 4 * 4));
    int* out_cnt        = (int*)(ws + alloc((size_t)N * 4));
    int* in_cnt         = (int*)(ws + alloc((size_t)N * 4));
    int* row_start      = (int*)(ws + alloc((size_t)(N + 1) * 4));
    int* cursor         = (int*)(ws + alloc((size_t)N * 4));
    int* bsum           = (int*)(ws + alloc((size_t)nb * 4));
    int* esrc           = (int*)(ws + alloc((size_t)E * 4));
    (void)ws_size;

    hipMemsetAsync(out_cnt, 0, (size_t)N * 4, stream);
    hipMemsetAsync(in_cnt, 0, (size_t)N * 4, stream);

    int n4each = HD * IN_F / 4;
    cvt_w_kernel<<<(2 * n4each + 255) / 256, 256, 0, stream>>>(
        (const float4*)W_fc, (const float4*)W_res, (ushort4*)w16, n4each);

    int eb = (E + 255) / 256;
    deg_kernel<<<eb, 256, 0, stream>>>(src, dst, out_cnt, in_cnt, E);
    scan1_kernel<<<nb, 256, 0, stream>>>(in_cnt, bsum, N);
    scan2_kernel<<<1, 256, 0, stream>>>(bsum, nb, row_start + N, E);
    scan3_kernel<<<nb, 256, 0, stream>>>(in_cnt, bsum, row_start, cursor, N);
    scatter_kernel<<<eb, 256, 0, stream>>>(src, dst, cursor, esrc, E);

    gemm_fused<<<(N + 63) / 64, 256, 0, stream>>>(feat, (const __hip_bfloat16*)w16,
                                                  out_cnt, attn_l, attn_r,
                                                  h16, el, er, out, N);

    int nb4 = (N + 3) / 4;
    agg_kernel<<<nb4, 256, 0, stream>>>(h16, el, er, row_start, esrc, out, N);
}

// Round 5
// 213.396 us; speedup vs baseline: 2.9690x; 1.0456x over previous
//
#include <hip/hip_runtime.h>
#include <hip/hip_bf16.h>
#include <math.h>

#define HD 128          // N_HEADS * OUT_FEATS
#define IN_F 256
#define NEG_SLOPE 0.2f

typedef __attribute__((ext_vector_type(8))) short short8;
typedef __attribute__((ext_vector_type(4))) float f32x4;

__device__ __forceinline__ unsigned short f2bf(float x) {
    __hip_bfloat16 b = __float2bfloat16(x);
    return *(unsigned short*)&b;
}
__device__ __forceinline__ float bf2f(unsigned short u) {
    unsigned int v = ((unsigned int)u) << 16;
    float f;
    __builtin_memcpy(&f, &v, 4);
    return f;
}

// ---------------- weights f32 -> bf16 ----------------
__global__ void cvt_w_kernel(const float4* __restrict__ wfc, const float4* __restrict__ wres,
                             ushort4* __restrict__ w16, int n4each) {
    int idx = blockIdx.x * blockDim.x + threadIdx.x;
    if (idx >= 2 * n4each) return;
    float4 f = (idx < n4each) ? wfc[idx] : wres[idx - n4each];
    ushort4 u;
    u.x = f2bf(f.x); u.y = f2bf(f.y); u.z = f2bf(f.z); u.w = f2bf(f.w);
    w16[idx] = u;
}

// ---------------- degree histogram + in-bucket rank ----------------
__global__ void deg_kernel(const int* __restrict__ src, const int* __restrict__ dst,
                           int* __restrict__ out_cnt, int* __restrict__ in_cnt,
                           int* __restrict__ off_e, int E) {
    int e = blockIdx.x * blockDim.x + threadIdx.x;
    if (e < E) {
        atomicAdd(&out_cnt[src[e]], 1);
        off_e[e] = atomicAdd(&in_cnt[dst[e]], 1);   // rank within dst bucket
    }
}

// ---------------- 3-phase parallel scan ----------------
__global__ __launch_bounds__(256) void scan1_kernel(const int* __restrict__ in_cnt,
                                                    int* __restrict__ bsum, int N) {
    __shared__ int wsum[4];
    int i = blockIdx.x * 256 + threadIdx.x;
    int v = (i < N) ? in_cnt[i] : 0;
#pragma unroll
    for (int d = 1; d < 64; d <<= 1) v += __shfl_xor(v, d);
    if ((threadIdx.x & 63) == 0) wsum[threadIdx.x >> 6] = v;
    __syncthreads();
    if (threadIdx.x == 0) bsum[blockIdx.x] = wsum[0] + wsum[1] + wsum[2] + wsum[3];
}

__global__ __launch_bounds__(256) void scan2_kernel(int* __restrict__ bsum, int nb,
                                                    int* __restrict__ row_start_N, int E) {
    __shared__ int wtot[4];
    int tid = threadIdx.x, lane = tid & 63, wid = tid >> 6;
    int v = (tid < nb) ? bsum[tid] : 0;
    int incl = v;
#pragma unroll
    for (int d = 1; d < 64; d <<= 1) {
        int t = __shfl_up(incl, d);
        if (lane >= d) incl += t;
    }
    if (lane == 63) wtot[wid] = incl;
    __syncthreads();
    int woff = 0;
    for (int w = 0; w < wid; w++) woff += wtot[w];
    if (tid < nb) bsum[tid] = woff + incl - v;  // exclusive block offset, in place
    if (tid == 0) *row_start_N = E;             // row_start[N]
}

__global__ __launch_bounds__(256) void scan3_kernel(const int* __restrict__ in_cnt,
                                                    const int* __restrict__ boff,
                                                    int* __restrict__ row_start, int N) {
    __shared__ int wsum[4];
    int i = blockIdx.x * 256 + threadIdx.x;
    int lane = threadIdx.x & 63, wid = threadIdx.x >> 6;
    int v = (i < N) ? in_cnt[i] : 0;
    int incl = v;
#pragma unroll
    for (int d = 1; d < 64; d <<= 1) {
        int t = __shfl_up(incl, d);
        if (lane >= d) incl += t;
    }
    if (lane == 63) wsum[wid] = incl;
    __syncthreads();
    int woff = 0;
    for (int w = 0; w < wid; w++) woff += wsum[w];
    int excl = boff[blockIdx.x] + woff + incl - v;
    if (i < N) row_start[i] = excl;
}

// ---------------- merged: GEMM tile (even blocks) | edge placement (odd blocks) ----
// GEMM: 64 rows x 256 cols per tile, 4 waves; cols 0..127 -> h16 + el/er,
// cols 128..255 -> residual into out. Place: esrc[row_start[dst]+off] = src.
__global__ __launch_bounds__(256) void gemm_place(
    const float* __restrict__ feat, const __hip_bfloat16* __restrict__ w16,
    const int* __restrict__ out_cnt, const float* __restrict__ attn_l,
    const float* __restrict__ attn_r, unsigned short* __restrict__ h16,
    float* __restrict__ el, float* __restrict__ er, float* __restrict__ out,
    const int* __restrict__ src, const int* __restrict__ dst,
    const int* __restrict__ off_e, const int* __restrict__ row_start,
    int* __restrict__ esrc, int N, int E) {
    __shared__ unsigned short sA[64 * 256];  // 32 KiB, XOR-swizzled 16B granules
    int tid = threadIdx.x;

    if (blockIdx.x & 1) {
        // ---- placement partition: no atomics, pure scatter ----
        int nP = gridDim.x >> 1;
        int stride = nP * 256;
        for (int e = (blockIdx.x >> 1) * 256 + tid; e < E; e += stride)
            esrc[row_start[dst[e]] + off_e[e]] = src[e];
        return;
    }

    int lane = tid & 63, wid = tid >> 6;
    int wn = wid;                 // 4 col panels of 64
    int bm = (blockIdx.x >> 1) * 64;
    int l15 = lane & 15, lg = lane >> 4;

    // ---- stage A: f32 -> bf16 into LDS (64 rows x 32 granules) ----
#pragma unroll
    for (int i = 0; i < 8; i++) {
        int G = i * 256 + tid;          // granule id
        int row = G >> 5, gc = G & 31;
        int gm = bm + row;
        gm = (gm < N) ? gm : (N - 1);
        const float4* fp = (const float4*)(feat + (size_t)gm * IN_F + gc * 8);
        float4 f0 = fp[0], f1 = fp[1];
        short8 v;
        v[0] = (short)f2bf(f0.x); v[1] = (short)f2bf(f0.y);
        v[2] = (short)f2bf(f0.z); v[3] = (short)f2bf(f0.w);
        v[4] = (short)f2bf(f1.x); v[5] = (short)f2bf(f1.y);
        v[6] = (short)f2bf(f1.z); v[7] = (short)f2bf(f1.w);
        *(short8*)&sA[row * 256 + ((gc ^ (row & 7)) * 8)] = v;
    }
    __syncthreads();

    int colbase = wn * 64;
    const __hip_bfloat16* bp[4];
#pragma unroll
    for (int ni = 0; ni < 4; ni++) {
        int c = colbase + ni * 16 + l15;  // 0..255
        bp[ni] = w16 + (size_t)c * IN_F + lg * 8;
    }

    f32x4 acc[4][4];
#pragma unroll
    for (int i = 0; i < 4; i++)
#pragma unroll
        for (int j = 0; j < 4; j++) acc[i][j] = (f32x4){0.f, 0.f, 0.f, 0.f};

#pragma unroll
    for (int k0 = 0; k0 < IN_F; k0 += 32) {
        short8 a[4], b[4];
#pragma unroll
        for (int mi = 0; mi < 4; mi++) {
            int row = mi * 16 + l15;
            int gs = ((k0 >> 3) + lg) ^ (row & 7);
            a[mi] = *(const short8*)&sA[row * 256 + gs * 8];
        }
#pragma unroll
        for (int ni = 0; ni < 4; ni++) b[ni] = *(const short8*)(bp[ni] + k0);
#pragma unroll
        for (int mi = 0; mi < 4; mi++)
#pragma unroll
            for (int ni = 0; ni < 4; ni++)
                acc[mi][ni] = __builtin_amdgcn_mfma_f32_16x16x32_bf16(
                    a[mi], b[ni], acc[mi][ni], 0, 0, 0);
    }

    // ---- epilogue. C/D layout: col = lane&15, row = 4*(lane>>4)+reg ----
    bool isH = (wn < 2);
    int colloc = colbase & 127;  // 0 or 64 within each half
    float alv[4], arv[4];
    if (isH) {
#pragma unroll
        for (int ni = 0; ni < 4; ni++) {
            int c = colbase + ni * 16 + l15;  // < 128; flat [H][32] == col index
            alv[ni] = attn_l[c];
            arv[ni] = attn_r[c];
        }
    }
#pragma unroll
    for (int mi = 0; mi < 4; mi++) {
#pragma unroll
        for (int reg = 0; reg < 4; reg++) {
            int r = bm + mi * 16 + lg * 4 + reg;
            bool valid = (r < N);
            int rr = valid ? r : 0;
            if (isH) {
                float nrm = rsqrtf(fmaxf((float)out_cnt[rr], 1.0f));
                float pl0 = 0.f, pl1 = 0.f, pr0 = 0.f, pr1 = 0.f;
#pragma unroll
                for (int ni = 0; ni < 4; ni++) {
                    float v = acc[mi][ni][reg];
                    if (valid)
                        h16[(size_t)r * HD + colloc + ni * 16 + l15] = f2bf(v * nrm);
                    if (ni < 2) { pl0 += v * alv[ni]; pr0 += v * arv[ni]; }
                    else        { pl1 += v * alv[ni]; pr1 += v * arv[ni]; }
                }
                pl0 *= nrm; pl1 *= nrm;  // el uses normalized h; er uses pre-norm h
#pragma unroll
                for (int m = 1; m < 16; m <<= 1) {
                    pl0 += __shfl_xor(pl0, m); pl1 += __shfl_xor(pl1, m);
                    pr0 += __shfl_xor(pr0, m); pr1 += __shfl_xor(pr1, m);
                }
                if (valid && (lane & 15) == 0) {
                    int hb = wn * 2;  // heads hb, hb+1
                    el[r * 4 + hb] = pl0;     el[r * 4 + hb + 1] = pl1;
                    er[r * 4 + hb] = pr0;     er[r * 4 + hb + 1] = pr1;
                }
            } else if (valid) {
#pragma unroll
                for (int ni = 0; ni < 4; ni++)
                    out[(size_t)r * HD + colloc + ni * 16 + l15] = acc[mi][ni][reg];
            }
        }
    }
}

// ---------------- fused edge softmax + weighted scatter + final ----------------
// One wave per dst node; 8-wide masked chunks for memory-level parallelism.
#define AGG_U 8
__global__ __launch_bounds__(256) void agg_kernel(const unsigned short* __restrict__ h16,
                                                  const float* __restrict__ el,
                                                  const float* __restrict__ er,
                                                  const int* __restrict__ row_start,
                                                  const int* __restrict__ esrc,
                                                  float* __restrict__ out, int N) {
    int wid = threadIdx.x >> 6, lane = threadIdx.x & 63;
    int n = blockIdx.x * 4 + wid;
    if (n >= N) return;
    int j0 = lane * 2;
    int h = lane >> 4;
    int beg = row_start[n], end = row_start[n + 1];
    float erh = er[n * 4 + h];
    float acc0 = 0.f, acc1 = 0.f, den = 0.f;
    for (int i = beg; i < end; i += AGG_U) {
        int s[AGG_U];
        bool ok[AGG_U];
#pragma unroll
        for (int u = 0; u < AGG_U; u++) {
            int idx = i + u;
            ok[u] = idx < end;
            s[u] = esrc[ok[u] ? idx : beg];
        }
        float ev[AGG_U];
        ushort2 v[AGG_U];
#pragma unroll
        for (int u = 0; u < AGG_U; u++) {
            ev[u] = el[s[u] * 4 + h];
            v[u] = *(const ushort2*)(h16 + (size_t)s[u] * HD + j0);
        }
#pragma unroll
        for (int u = 0; u < AGG_U; u++) {
            float e = ev[u] + erh;
            e = (e > 0.f) ? e : NEG_SLOPE * e;
            float ex = ok[u] ? __expf(e) : 0.f;
            den += ex;
            acc0 += ex * bf2f(v[u].x);
            acc1 += ex * bf2f(v[u].y);
        }
    }
    float2 res = *(const float2*)(out + (size_t)n * HD + j0);
    float o0 = res.x, o1 = res.y;
    int indeg = end - beg;
    if (indeg > 0) {
        float sc = sqrtf((float)indeg) / den;  // sqrt(clip(in_deg,1)) / denom
        o0 += sc * acc0;
        o1 += sc * acc1;
    }
    *(float2*)(out + (size_t)n * HD + j0) = make_float2(o0, o1);
}

extern "C" void kernel_launch(void* const* d_in, const int* in_sizes, int n_in,
                              void* d_out, int out_size, void* d_ws, size_t ws_size,
                              hipStream_t stream) {
    const float* feat   = (const float*)d_in[0];
    const int*   src    = (const int*)d_in[1];
    const int*   dst    = (const int*)d_in[2];
    const float* W_fc   = (const float*)d_in[3];
    const float* attn_l = (const float*)d_in[4];
    const float* attn_r = (const float*)d_in[5];
    const float* W_res  = (const float*)d_in[6];
    float* out = (float*)d_out;

    int N = in_sizes[0] / IN_F;   // 50000
    int E = in_sizes[1];          // 800000
    int nb = (N + 255) / 256;     // 196 (<= 256 for scan2)

    size_t off = 0;
    auto alloc = [&](size_t bytes) {
        size_t o = off;
        off = (off + bytes + 255) & ~(size_t)255;
        return o;
    };
    char* ws = (char*)d_ws;
    unsigned short* h16 = (unsigned short*)(ws + alloc((size_t)N * HD * 2));
    __hip_bfloat16* w16 = (__hip_bfloat16*)(ws + alloc((size_t)2 * HD * IN_F * 2));
    float* el           = (float*)(ws + alloc((size_t)N * 4 * 4));
    float* er           = (float*)(ws + alloc((size_t)N * 4 * 4));
    int* out_cnt        = (int*)(ws + alloc((size_t)N * 4));
    int* in_cnt         = (int*)(ws + alloc((size_t)N * 4));
    int* row_start      = (int*)(ws + alloc((size_t)(N + 1) * 4));
    int* bsum           = (int*)(ws + alloc((size_t)nb * 4));
    int* off_e          = (int*)(ws + alloc((size_t)E * 4));
    int* esrc           = (int*)(ws + alloc((size_t)E * 4));
    (void)ws_size;

    hipMemsetAsync(out_cnt, 0, (size_t)N * 4, stream);
    hipMemsetAsync(in_cnt, 0, (size_t)N * 4, stream);

    int n4each = HD * IN_F / 4;
    cvt_w_kernel<<<(2 * n4each + 255) / 256, 256, 0, stream>>>(
        (const float4*)W_fc, (const float4*)W_res, (ushort4*)w16, n4each);

    int eb = (E + 255) / 256;
    deg_kernel<<<eb, 256, 0, stream>>>(src, dst, out_cnt, in_cnt, off_e, E);
    scan1_kernel<<<nb, 256, 0, stream>>>(in_cnt, bsum, N);
    scan2_kernel<<<1, 256, 0, stream>>>(bsum, nb, row_start + N, E);
    scan3_kernel<<<nb, 256, 0, stream>>>(in_cnt, bsum, row_start, N);

    int gb = (N + 63) / 64;                    // 782 gemm tile blocks
    gemm_place<<<2 * gb, 256, 0, stream>>>(feat, (const __hip_bfloat16*)w16,
                                           out_cnt, attn_l, attn_r,
                                           h16, el, er, out,
                                           src, dst, off_e, row_start, esrc, N, E);

    int nb4 = (N + 3) / 4;
    agg_kernel<<<nb4, 256, 0, stream>>>(h16, el, er, row_start, esrc, out, N);
}

// Round 6
// 173.006 us; speedup vs baseline: 3.6621x; 1.2335x over previous
//
#include <hip/hip_runtime.h>
#include <hip/hip_bf16.h>
#include <math.h>

#define HD 128          // N_HEADS * OUT_FEATS
#define IN_F 256
#define NEG_SLOPE 0.2f
#define NMAX 50000      // problem-fixed node count (LDS histogram capacity)
#define C_CHUNKS 32

typedef __attribute__((ext_vector_type(8))) short short8;
typedef __attribute__((ext_vector_type(4))) float f32x4;

__device__ __forceinline__ unsigned short f2bf(float x) {
    __hip_bfloat16 b = __float2bfloat16(x);
    return *(unsigned short*)&b;
}
__device__ __forceinline__ float bf2f(unsigned short u) {
    unsigned int v = ((unsigned int)u) << 16;
    float f;
    __builtin_memcpy(&f, &v, 4);
    return f;
}

// ---------------- weights f32 -> bf16 ----------------
__global__ void cvt_w_kernel(const float4* __restrict__ wfc, const float4* __restrict__ wres,
                             ushort4* __restrict__ w16, int n4each) {
    int idx = blockIdx.x * blockDim.x + threadIdx.x;
    if (idx >= 2 * n4each) return;
    float4 f = (idx < n4each) ? wfc[idx] : wres[idx - n4each];
    ushort4 u;
    u.x = f2bf(f.x); u.y = f2bf(f.y); u.z = f2bf(f.z); u.w = f2bf(f.w);
    w16[idx] = u;
}

// ---------------- per-chunk LDS histogram (uint16-packed, no global atomics) ----
// grid (C_CHUNKS, 2): y==0 -> histogram dst into pc_dst, y==1 -> src into pc_src.
__global__ __launch_bounds__(512) void hist_kernel(const int* __restrict__ src,
                                                   const int* __restrict__ dst,
                                                   unsigned short* __restrict__ pc_src,
                                                   unsigned short* __restrict__ pc_dst,
                                                   int N, int E, int chunk) {
    __shared__ unsigned int h[NMAX / 2];   // 100 KB packed uint16 counts
    int tid = threadIdx.x;
    int nh = N >> 1;                        // N even
    uint4* h4 = (uint4*)h;
    for (int i = tid; i < (nh >> 2); i += 512) h4[i] = make_uint4(0, 0, 0, 0);
    for (int i = (nh & ~3) + tid; i < nh; i += 512) h[i] = 0;
    __syncthreads();

    const int* arr = blockIdx.y ? src : dst;
    int e1 = min(E, (int)(blockIdx.x + 1) * chunk);
    for (int e = blockIdx.x * chunk + tid; e < e1; e += 512) {
        int v = arr[e];
        atomicAdd(&h[v >> 1], 1u << ((v & 1) << 4));
    }
    __syncthreads();

    unsigned short* pc = (blockIdx.y ? pc_src : pc_dst) + (size_t)blockIdx.x * N;
    uint4* pc4 = (uint4*)pc;
    for (int i = tid; i < (nh >> 2); i += 512) pc4[i] = h4[i];
    for (int i = (nh & ~3) + tid; i < nh; i += 512) ((unsigned int*)pc)[i] = h[i];
}

// ---------------- per-node chunk-prefix + degree sums (replaces atomic deg) ----
__global__ __launch_bounds__(256) void sum_kernel(const unsigned short* __restrict__ pc_src,
                                                  const unsigned short* __restrict__ pc_dst,
                                                  unsigned short* __restrict__ chunkpre,
                                                  int* __restrict__ out_cnt,
                                                  int* __restrict__ deg, int N) {
    int n = blockIdx.x * 256 + threadIdx.x;
    if (n >= N) return;
    int ss = 0, sd = 0;
#pragma unroll
    for (int c = 0; c < C_CHUNKS; c++) {
        ss += pc_src[(size_t)c * N + n];
        unsigned short v = pc_dst[(size_t)c * N + n];
        chunkpre[(size_t)c * N + n] = (unsigned short)sd;
        sd += v;
    }
    out_cnt[n] = ss;
    deg[n] = sd;
}

// ---------------- 3-phase parallel scan over deg ----------------
__global__ __launch_bounds__(256) void scan1_kernel(const int* __restrict__ deg,
                                                    int* __restrict__ bsum, int N) {
    __shared__ int wsum[4];
    int i = blockIdx.x * 256 + threadIdx.x;
    int v = (i < N) ? deg[i] : 0;
#pragma unroll
    for (int d = 1; d < 64; d <<= 1) v += __shfl_xor(v, d);
    if ((threadIdx.x & 63) == 0) wsum[threadIdx.x >> 6] = v;
    __syncthreads();
    if (threadIdx.x == 0) bsum[blockIdx.x] = wsum[0] + wsum[1] + wsum[2] + wsum[3];
}

__global__ __launch_bounds__(256) void scan2_kernel(int* __restrict__ bsum, int nb,
                                                    int* __restrict__ row_start_N, int E) {
    __shared__ int wtot[4];
    int tid = threadIdx.x, lane = tid & 63, wid = tid >> 6;
    int v = (tid < nb) ? bsum[tid] : 0;
    int incl = v;
#pragma unroll
    for (int d = 1; d < 64; d <<= 1) {
        int t = __shfl_up(incl, d);
        if (lane >= d) incl += t;
    }
    if (lane == 63) wtot[wid] = incl;
    __syncthreads();
    int woff = 0;
    for (int w = 0; w < wid; w++) woff += wtot[w];
    if (tid < nb) bsum[tid] = woff + incl - v;  // exclusive block offset, in place
    if (tid == 0) *row_start_N = E;             // row_start[N]
}

__global__ __launch_bounds__(256) void scan3_kernel(const int* __restrict__ deg,
                                                    const int* __restrict__ boff,
                                                    int* __restrict__ row_start, int N) {
    __shared__ int wsum[4];
    int i = blockIdx.x * 256 + threadIdx.x;
    int lane = threadIdx.x & 63, wid = threadIdx.x >> 6;
    int v = (i < N) ? deg[i] : 0;
    int incl = v;
#pragma unroll
    for (int d = 1; d < 64; d <<= 1) {
        int t = __shfl_up(incl, d);
        if (lane >= d) incl += t;
    }
    if (lane == 63) wsum[wid] = incl;
    __syncthreads();
    int woff = 0;
    for (int w = 0; w < wid; w++) woff += wsum[w];
    int excl = boff[blockIdx.x] + woff + incl - v;
    if (i < N) row_start[i] = excl;
}

// ---------------- placement: LDS cursors, no global atomics ----------------
__global__ __launch_bounds__(512) void place_kernel(const int* __restrict__ src,
                                                    const int* __restrict__ dst,
                                                    const unsigned short* __restrict__ chunkpre,
                                                    const int* __restrict__ row_start,
                                                    int* __restrict__ esrc,
                                                    int N, int E, int chunk) {
    __shared__ unsigned int cur[NMAX / 2];   // packed uint16 cursors
    int tid = threadIdx.x;
    int nh = N >> 1;
    const uint4* cp4 = (const uint4*)(chunkpre + (size_t)blockIdx.x * N);
    uint4* cur4 = (uint4*)cur;
    for (int i = tid; i < (nh >> 2); i += 512) cur4[i] = cp4[i];
    for (int i = (nh & ~3) + tid; i < nh; i += 512)
        cur[i] = ((const unsigned int*)(chunkpre + (size_t)blockIdx.x * N))[i];
    __syncthreads();

    int e1 = min(E, (int)(blockIdx.x + 1) * chunk);
    for (int e = blockIdx.x * chunk + tid; e < e1; e += 512) {
        int d = dst[e], s = src[e];
        int sh = (d & 1) << 4;
        unsigned int old = atomicAdd(&cur[d >> 1], 1u << sh);
        int rank = (old >> sh) & 0xffff;
        esrc[row_start[d] + rank] = s;
    }
}

// ---------------- fused GEMM: cvt(A)->LDS, MFMA, epilogue norm + el/er ----------------
// Block: 64 rows x 256 cols, 4 waves; cols 0..127 -> h16 + el/er, 128..255 -> resid.
__global__ __launch_bounds__(256) void gemm_fused(
    const float* __restrict__ feat, const __hip_bfloat16* __restrict__ w16,
    const int* __restrict__ out_cnt, const float* __restrict__ attn_l,
    const float* __restrict__ attn_r, unsigned short* __restrict__ h16,
    float* __restrict__ el, float* __restrict__ er, float* __restrict__ out, int N) {
    __shared__ unsigned short sA[64 * 256];  // 32 KiB, XOR-swizzled 16B granules
    int tid = threadIdx.x;
    int lane = tid & 63, wid = tid >> 6;
    int wn = wid;                 // 4 col panels of 64
    int bm = blockIdx.x * 64;
    int l15 = lane & 15, lg = lane >> 4;

    // ---- stage A: f32 -> bf16 into LDS (64 rows x 32 granules) ----
#pragma unroll
    for (int i = 0; i < 8; i++) {
        int G = i * 256 + tid;          // granule id
        int row = G >> 5, gc = G & 31;
        int gm = bm + row;
        gm = (gm < N) ? gm : (N - 1);
        const float4* fp = (const float4*)(feat + (size_t)gm * IN_F + gc * 8);
        float4 f0 = fp[0], f1 = fp[1];
        short8 v;
        v[0] = (short)f2bf(f0.x); v[1] = (short)f2bf(f0.y);
        v[2] = (short)f2bf(f0.z); v[3] = (short)f2bf(f0.w);
        v[4] = (short)f2bf(f1.x); v[5] = (short)f2bf(f1.y);
        v[6] = (short)f2bf(f1.z); v[7] = (short)f2bf(f1.w);
        *(short8*)&sA[row * 256 + ((gc ^ (row & 7)) * 8)] = v;
    }
    __syncthreads();

    int colbase = wn * 64;
    const __hip_bfloat16* bp[4];
#pragma unroll
    for (int ni = 0; ni < 4; ni++) {
        int c = colbase + ni * 16 + l15;  // 0..255
        bp[ni] = w16 + (size_t)c * IN_F + lg * 8;
    }

    f32x4 acc[4][4];
#pragma unroll
    for (int i = 0; i < 4; i++)
#pragma unroll
        for (int j = 0; j < 4; j++) acc[i][j] = (f32x4){0.f, 0.f, 0.f, 0.f};

#pragma unroll
    for (int k0 = 0; k0 < IN_F; k0 += 32) {
        short8 a[4], b[4];
#pragma unroll
        for (int mi = 0; mi < 4; mi++) {
            int row = mi * 16 + l15;
            int gs = ((k0 >> 3) + lg) ^ (row & 7);
            a[mi] = *(const short8*)&sA[row * 256 + gs * 8];
        }
#pragma unroll
        for (int ni = 0; ni < 4; ni++) b[ni] = *(const short8*)(bp[ni] + k0);
#pragma unroll
        for (int mi = 0; mi < 4; mi++)
#pragma unroll
            for (int ni = 0; ni < 4; ni++)
                acc[mi][ni] = __builtin_amdgcn_mfma_f32_16x16x32_bf16(
                    a[mi], b[ni], acc[mi][ni], 0, 0, 0);
    }

    // ---- epilogue. C/D layout: col = lane&15, row = 4*(lane>>4)+reg ----
    bool isH = (wn < 2);
    int colloc = colbase & 127;  // 0 or 64 within each half
    float alv[4], arv[4];
    if (isH) {
#pragma unroll
        for (int ni = 0; ni < 4; ni++) {
            int c = colbase + ni * 16 + l15;  // < 128; flat [H][32] == col index
            alv[ni] = attn_l[c];
            arv[ni] = attn_r[c];
        }
    }
#pragma unroll
    for (int mi = 0; mi < 4; mi++) {
#pragma unroll
        for (int reg = 0; reg < 4; reg++) {
            int r = bm + mi * 16 + lg * 4 + reg;
            bool valid = (r < N);
            int rr = valid ? r : 0;
            if (isH) {
                float nrm = rsqrtf(fmaxf((float)out_cnt[rr], 1.0f));
                float pl0 = 0.f, pl1 = 0.f, pr0 = 0.f, pr1 = 0.f;
#pragma unroll
                for (int ni = 0; ni < 4; ni++) {
                    float v = acc[mi][ni][reg];
                    if (valid)
                        h16[(size_t)r * HD + colloc + ni * 16 + l15] = f2bf(v * nrm);
                    if (ni < 2) { pl0 += v * alv[ni]; pr0 += v * arv[ni]; }
                    else        { pl1 += v * alv[ni]; pr1 += v * arv[ni]; }
                }
                pl0 *= nrm; pl1 *= nrm;  // el uses normalized h; er uses pre-norm h
#pragma unroll
                for (int m = 1; m < 16; m <<= 1) {
                    pl0 += __shfl_xor(pl0, m); pl1 += __shfl_xor(pl1, m);
                    pr0 += __shfl_xor(pr0, m); pr1 += __shfl_xor(pr1, m);
                }
                if (valid && (lane & 15) == 0) {
                    int hb = wn * 2;  // heads hb, hb+1
                    el[r * 4 + hb] = pl0;     el[r * 4 + hb + 1] = pl1;
                    er[r * 4 + hb] = pr0;     er[r * 4 + hb + 1] = pr1;
                }
            } else if (valid) {
#pragma unroll
                for (int ni = 0; ni < 4; ni++)
                    out[(size_t)r * HD + colloc + ni * 16 + l15] = acc[mi][ni][reg];
            }
        }
    }
}

// ---------------- fused edge softmax + weighted scatter + final ----------------
#define AGG_U 8
__global__ __launch_bounds__(256) void agg_kernel(const unsigned short* __restrict__ h16,
                                                  const float* __restrict__ el,
                                                  const float* __restrict__ er,
                                                  const int* __restrict__ row_start,
                                                  const int* __restrict__ esrc,
                                                  float* __restrict__ out, int N) {
    int wid = threadIdx.x >> 6, lane = threadIdx.x & 63;
    int n = blockIdx.x * 4 + wid;
    if (n >= N) return;
    int j0 = lane * 2;
    int h = lane >> 4;
    int beg = row_start[n], end = row_start[n + 1];
    float erh = er[n * 4 + h];
    float acc0 = 0.f, acc1 = 0.f, den = 0.f;
    for (int i = beg; i < end; i += AGG_U) {
        int s[AGG_U];
        bool ok[AGG_U];
#pragma unroll
        for (int u = 0; u < AGG_U; u++) {
            int idx = i + u;
            ok[u] = idx < end;
            s[u] = esrc[ok[u] ? idx : beg];
        }
        float ev[AGG_U];
        ushort2 v[AGG_U];
#pragma unroll
        for (int u = 0; u < AGG_U; u++) {
            ev[u] = el[s[u] * 4 + h];
            v[u] = *(const ushort2*)(h16 + (size_t)s[u] * HD + j0);
        }
#pragma unroll
        for (int u = 0; u < AGG_U; u++) {
            float e = ev[u] + erh;
            e = (e > 0.f) ? e : NEG_SLOPE * e;
            float ex = ok[u] ? __expf(e) : 0.f;
            den += ex;
            acc0 += ex * bf2f(v[u].x);
            acc1 += ex * bf2f(v[u].y);
        }
    }
    float2 res = *(const float2*)(out + (size_t)n * HD + j0);
    float o0 = res.x, o1 = res.y;
    int indeg = end - beg;
    if (indeg > 0) {
        float sc = sqrtf((float)indeg) / den;  // sqrt(clip(in_deg,1)) / denom
        o0 += sc * acc0;
        o1 += sc * acc1;
    }
    *(float2*)(out + (size_t)n * HD + j0) = make_float2(o0, o1);
}

extern "C" void kernel_launch(void* const* d_in, const int* in_sizes, int n_in,
                              void* d_out, int out_size, void* d_ws, size_t ws_size,
                              hipStream_t stream) {
    const float* feat   = (const float*)d_in[0];
    const int*   src    = (const int*)d_in[1];
    const int*   dst    = (const int*)d_in[2];
    const float* W_fc   = (const float*)d_in[3];
    const float* attn_l = (const float*)d_in[4];
    const float* attn_r = (const float*)d_in[5];
    const float* W_res  = (const float*)d_in[6];
    float* out = (float*)d_out;

    int N = in_sizes[0] / IN_F;   // 50000
    int E = in_sizes[1];          // 800000
    int nb = (N + 255) / 256;     // 196 (<= 256 for scan2)
    int chunk = (E + C_CHUNKS - 1) / C_CHUNKS;

    size_t off = 0;
    auto alloc = [&](size_t bytes) {
        size_t o = off;
        off = (off + bytes + 255) & ~(size_t)255;
        return o;
    };
    char* ws = (char*)d_ws;
    unsigned short* h16      = (unsigned short*)(ws + alloc((size_t)N * HD * 2));
    __hip_bfloat16* w16      = (__hip_bfloat16*)(ws + alloc((size_t)2 * HD * IN_F * 2));
    float* el                = (float*)(ws + alloc((size_t)N * 4 * 4));
    float* er                = (float*)(ws + alloc((size_t)N * 4 * 4));
    int* out_cnt             = (int*)(ws + alloc((size_t)N * 4));
    int* deg                 = (int*)(ws + alloc((size_t)N * 4));
    int* row_start           = (int*)(ws + alloc((size_t)(N + 1) * 4));
    int* bsum                = (int*)(ws + alloc((size_t)nb * 4));
    unsigned short* pc_src   = (unsigned short*)(ws + alloc((size_t)C_CHUNKS * N * 2));
    unsigned short* pc_dst   = (unsigned short*)(ws + alloc((size_t)C_CHUNKS * N * 2));
    unsigned short* chunkpre = (unsigned short*)(ws + alloc((size_t)C_CHUNKS * N * 2));
    int* esrc                = (int*)(ws + alloc((size_t)E * 4));
    (void)ws_size;

    int n4each = HD * IN_F / 4;
    cvt_w_kernel<<<(2 * n4each + 255) / 256, 256, 0, stream>>>(
        (const float4*)W_fc, (const float4*)W_res, (ushort4*)w16, n4each);

    hist_kernel<<<dim3(C_CHUNKS, 2), 512, 0, stream>>>(src, dst, pc_src, pc_dst,
                                                       N, E, chunk);
    sum_kernel<<<nb, 256, 0, stream>>>(pc_src, pc_dst, chunkpre, out_cnt, deg, N);
    scan1_kernel<<<nb, 256, 0, stream>>>(deg, bsum, N);
    scan2_kernel<<<1, 256, 0, stream>>>(bsum, nb, row_start + N, E);
    scan3_kernel<<<nb, 256, 0, stream>>>(deg, bsum, row_start, N);
    place_kernel<<<C_CHUNKS, 512, 0, stream>>>(src, dst, chunkpre, row_start, esrc,
                                               N, E, chunk);

    gemm_fused<<<(N + 63) / 64, 256, 0, stream>>>(feat, (const __hip_bfloat16*)w16,
                                                  out_cnt, attn_l, attn_r,
                                                  h16, el, er, out, N);

    int nb4 = (N + 3) / 4;
    agg_kernel<<<nb4, 256, 0, stream>>>(h16, el, er, row_start, esrc, out, N);
}

// Round 7
// 167.954 us; speedup vs baseline: 3.7723x; 1.0301x over previous
//
#include <hip/hip_runtime.h>
#include <hip/hip_bf16.h>
#include <math.h>

#define HD 128          // N_HEADS * OUT_FEATS
#define IN_F 256
#define NEG_SLOPE 0.2f
#define NMAX 50000      // problem-fixed node count (LDS histogram capacity)

typedef __attribute__((ext_vector_type(8))) short short8;
typedef __attribute__((ext_vector_type(4))) float f32x4;

__device__ __forceinline__ unsigned short f2bf(float x) {
    __hip_bfloat16 b = __float2bfloat16(x);
    return *(unsigned short*)&b;
}
__device__ __forceinline__ float bf2f(unsigned short u) {
    unsigned int v = ((unsigned int)u) << 16;
    float f;
    __builtin_memcpy(&f, &v, 4);
    return f;
}

// ---------------- weights f32 -> bf16 ----------------
__global__ void cvt_w_kernel(const float4* __restrict__ wfc, const float4* __restrict__ wres,
                             ushort4* __restrict__ w16, int n4each) {
    int idx = blockIdx.x * blockDim.x + threadIdx.x;
    if (idx >= 2 * n4each) return;
    float4 f = (idx < n4each) ? wfc[idx] : wres[idx - n4each];
    ushort4 u;
    u.x = f2bf(f.x); u.y = f2bf(f.y); u.z = f2bf(f.z); u.w = f2bf(f.w);
    w16[idx] = u;
}

// ---------------- per-chunk LDS histogram (uint16-packed, no global atomics) ----
// grid (C, 2): y==0 -> histogram dst into pc_dst, y==1 -> src into pc_src.
__global__ __launch_bounds__(512) void hist_kernel(const int* __restrict__ src,
                                                   const int* __restrict__ dst,
                                                   unsigned short* __restrict__ pc_src,
                                                   unsigned short* __restrict__ pc_dst,
                                                   int N, int E, int chunk) {
    __shared__ unsigned int h[NMAX / 2];   // 100 KB packed uint16 counts
    int tid = threadIdx.x;
    int nh = N >> 1;                        // N even
    uint4* h4 = (uint4*)h;
    for (int i = tid; i < (nh >> 2); i += 512) h4[i] = make_uint4(0, 0, 0, 0);
    for (int i = (nh & ~3) + tid; i < nh; i += 512) h[i] = 0;
    __syncthreads();

    const int* arr = blockIdx.y ? src : dst;
    int e1 = min(E, (int)(blockIdx.x + 1) * chunk);
    for (int e = blockIdx.x * chunk + tid; e < e1; e += 512) {
        int v = arr[e];
        atomicAdd(&h[v >> 1], 1u << ((v & 1) << 4));
    }
    __syncthreads();

    unsigned short* pc = (blockIdx.y ? pc_src : pc_dst) + (size_t)blockIdx.x * N;
    uint4* pc4 = (uint4*)pc;
    for (int i = tid; i < (nh >> 2); i += 512) pc4[i] = h4[i];
    for (int i = (nh & ~3) + tid; i < nh; i += 512) ((unsigned int*)pc)[i] = h[i];
}

// ---------------- per-node chunk prefix (in place) + degrees + scan1 ----------------
__global__ __launch_bounds__(256) void sum_scan1_kernel(
    const unsigned short* __restrict__ pc_src, unsigned short* __restrict__ pc_dst,
    int* __restrict__ out_cnt, int* __restrict__ deg, int* __restrict__ bsum,
    int N, int C) {
    __shared__ int wsum[4];
    int n = blockIdx.x * 256 + threadIdx.x;
    int sd = 0;
    if (n < N) {
        int ss = 0;
        for (int c = 0; c < C; c++) {
            ss += pc_src[(size_t)c * N + n];
            unsigned short v = pc_dst[(size_t)c * N + n];
            pc_dst[(size_t)c * N + n] = (unsigned short)sd;  // exclusive chunk prefix
            sd += v;
        }
        out_cnt[n] = ss;
        deg[n] = sd;
    }
    int v = (n < N) ? sd : 0;
#pragma unroll
    for (int d = 1; d < 64; d <<= 1) v += __shfl_xor(v, d);
    if ((threadIdx.x & 63) == 0) wsum[threadIdx.x >> 6] = v;
    __syncthreads();
    if (threadIdx.x == 0) bsum[blockIdx.x] = wsum[0] + wsum[1] + wsum[2] + wsum[3];
}

// ---------------- scan of block sums + scatter of row_start ----------------
__global__ __launch_bounds__(256) void scan2_kernel(int* __restrict__ bsum, int nb,
                                                    int* __restrict__ row_start_N, int E) {
    __shared__ int wtot[4];
    int tid = threadIdx.x, lane = tid & 63, wid = tid >> 6;
    int v = (tid < nb) ? bsum[tid] : 0;
    int incl = v;
#pragma unroll
    for (int d = 1; d < 64; d <<= 1) {
        int t = __shfl_up(incl, d);
        if (lane >= d) incl += t;
    }
    if (lane == 63) wtot[wid] = incl;
    __syncthreads();
    int woff = 0;
    for (int w = 0; w < wid; w++) woff += wtot[w];
    if (tid < nb) bsum[tid] = woff + incl - v;  // exclusive block offset, in place
    if (tid == 0) *row_start_N = E;             // row_start[N]
}

__global__ __launch_bounds__(256) void scan3_kernel(const int* __restrict__ deg,
                                                    const int* __restrict__ boff,
                                                    int* __restrict__ row_start, int N) {
    __shared__ int wsum[4];
    int i = blockIdx.x * 256 + threadIdx.x;
    int lane = threadIdx.x & 63, wid = threadIdx.x >> 6;
    int v = (i < N) ? deg[i] : 0;
    int incl = v;
#pragma unroll
    for (int d = 1; d < 64; d <<= 1) {
        int t = __shfl_up(incl, d);
        if (lane >= d) incl += t;
    }
    if (lane == 63) wsum[wid] = incl;
    __syncthreads();
    int woff = 0;
    for (int w = 0; w < wid; w++) woff += wsum[w];
    int excl = boff[blockIdx.x] + woff + incl - v;
    if (i < N) row_start[i] = excl;
}

// ---------------- placement: LDS cursors seeded from chunk prefix ----------------
__global__ __launch_bounds__(512) void place_kernel(const int* __restrict__ src,
                                                    const int* __restrict__ dst,
                                                    const unsigned short* __restrict__ chunkpre,
                                                    const int* __restrict__ row_start,
                                                    int* __restrict__ esrc,
                                                    int N, int E, int chunk) {
    __shared__ unsigned int cur[NMAX / 2];   // packed uint16 cursors
    int tid = threadIdx.x;
    int nh = N >> 1;
    const unsigned short* cp = chunkpre + (size_t)blockIdx.x * N;
    const uint4* cp4 = (const uint4*)cp;
    uint4* cur4 = (uint4*)cur;
    for (int i = tid; i < (nh >> 2); i += 512) cur4[i] = cp4[i];
    for (int i = (nh & ~3) + tid; i < nh; i += 512) cur[i] = ((const unsigned int*)cp)[i];
    __syncthreads();

    int e1 = min(E, (int)(blockIdx.x + 1) * chunk);
    for (int e = blockIdx.x * chunk + tid; e < e1; e += 512) {
        int d = dst[e], s = src[e];
        int sh = (d & 1) << 4;
        unsigned int old = atomicAdd(&cur[d >> 1], 1u << sh);
        int rank = (old >> sh) & 0xffff;
        esrc[row_start[d] + rank] = s;
    }
}

// ---------------- fused GEMM: cvt(A)->LDS, MFMA, epilogue norm + el/er ----------------
// Block: 64 rows x 256 cols, 4 waves; cols 0..127 -> h16 + el/er, 128..255 -> resid.
__global__ __launch_bounds__(256) void gemm_fused(
    const float* __restrict__ feat, const __hip_bfloat16* __restrict__ w16,
    const int* __restrict__ out_cnt, const float* __restrict__ attn_l,
    const float* __restrict__ attn_r, unsigned short* __restrict__ h16,
    float* __restrict__ el, float* __restrict__ er, float* __restrict__ out, int N) {
    __shared__ unsigned short sA[64 * 256];  // 32 KiB, XOR-swizzled 16B granules
    int tid = threadIdx.x;
    int lane = tid & 63, wid = tid >> 6;
    int wn = wid;                 // 4 col panels of 64
    int bm = blockIdx.x * 64;
    int l15 = lane & 15, lg = lane >> 4;

    // ---- stage A: f32 -> bf16 into LDS (64 rows x 32 granules) ----
#pragma unroll
    for (int i = 0; i < 8; i++) {
        int G = i * 256 + tid;          // granule id
        int row = G >> 5, gc = G & 31;
        int gm = bm + row;
        gm = (gm < N) ? gm : (N - 1);
        const float4* fp = (const float4*)(feat + (size_t)gm * IN_F + gc * 8);
        float4 f0 = fp[0], f1 = fp[1];
        short8 v;
        v[0] = (short)f2bf(f0.x); v[1] = (short)f2bf(f0.y);
        v[2] = (short)f2bf(f0.z); v[3] = (short)f2bf(f0.w);
        v[4] = (short)f2bf(f1.x); v[5] = (short)f2bf(f1.y);
        v[6] = (short)f2bf(f1.z); v[7] = (short)f2bf(f1.w);
        *(short8*)&sA[row * 256 + ((gc ^ (row & 7)) * 8)] = v;
    }
    __syncthreads();

    int colbase = wn * 64;
    const __hip_bfloat16* bp[4];
#pragma unroll
    for (int ni = 0; ni < 4; ni++) {
        int c = colbase + ni * 16 + l15;  // 0..255
        bp[ni] = w16 + (size_t)c * IN_F + lg * 8;
    }

    f32x4 acc[4][4];
#pragma unroll
    for (int i = 0; i < 4; i++)
#pragma unroll
        for (int j = 0; j < 4; j++) acc[i][j] = (f32x4){0.f, 0.f, 0.f, 0.f};

#pragma unroll
    for (int k0 = 0; k0 < IN_F; k0 += 32) {
        short8 a[4], b[4];
#pragma unroll
        for (int mi = 0; mi < 4; mi++) {
            int row = mi * 16 + l15;
            int gs = ((k0 >> 3) + lg) ^ (row & 7);
            a[mi] = *(const short8*)&sA[row * 256 + gs * 8];
        }
#pragma unroll
        for (int ni = 0; ni < 4; ni++) b[ni] = *(const short8*)(bp[ni] + k0);
#pragma unroll
        for (int mi = 0; mi < 4; mi++)
#pragma unroll
            for (int ni = 0; ni < 4; ni++)
                acc[mi][ni] = __builtin_amdgcn_mfma_f32_16x16x32_bf16(
                    a[mi], b[ni], acc[mi][ni], 0, 0, 0);
    }

    // ---- epilogue. C/D layout: col = lane&15, row = 4*(lane>>4)+reg ----
    bool isH = (wn < 2);
    int colloc = colbase & 127;  // 0 or 64 within each half
    float alv[4], arv[4];
    if (isH) {
#pragma unroll
        for (int ni = 0; ni < 4; ni++) {
            int c = colbase + ni * 16 + l15;  // < 128; flat [H][32] == col index
            alv[ni] = attn_l[c];
            arv[ni] = attn_r[c];
        }
    }
#pragma unroll
    for (int mi = 0; mi < 4; mi++) {
#pragma unroll
        for (int reg = 0; reg < 4; reg++) {
            int r = bm + mi * 16 + lg * 4 + reg;
            bool valid = (r < N);
            int rr = valid ? r : 0;
            if (isH) {
                float nrm = rsqrtf(fmaxf((float)out_cnt[rr], 1.0f));
                float pl0 = 0.f, pl1 = 0.f, pr0 = 0.f, pr1 = 0.f;
#pragma unroll
                for (int ni = 0; ni < 4; ni++) {
                    float v = acc[mi][ni][reg];
                    if (valid)
                        h16[(size_t)r * HD + colloc + ni * 16 + l15] = f2bf(v * nrm);
                    if (ni < 2) { pl0 += v * alv[ni]; pr0 += v * arv[ni]; }
                    else        { pl1 += v * alv[ni]; pr1 += v * arv[ni]; }
                }
                pl0 *= nrm; pl1 *= nrm;  // el uses normalized h; er uses pre-norm h
#pragma unroll
                for (int m = 1; m < 16; m <<= 1) {
                    pl0 += __shfl_xor(pl0, m); pl1 += __shfl_xor(pl1, m);
                    pr0 += __shfl_xor(pr0, m); pr1 += __shfl_xor(pr1, m);
                }
                if (valid && (lane & 15) == 0) {
                    int hb = wn * 2;  // heads hb, hb+1
                    el[r * 4 + hb] = pl0;     el[r * 4 + hb + 1] = pl1;
                    er[r * 4 + hb] = pr0;     er[r * 4 + hb + 1] = pr1;
                }
            } else if (valid) {
#pragma unroll
                for (int ni = 0; ni < 4; ni++)
                    out[(size_t)r * HD + colloc + ni * 16 + l15] = acc[mi][ni][reg];
            }
        }
    }
}

// ---------------- fused edge softmax + weighted scatter + final ----------------
#define AGG_U 8
__global__ __launch_bounds__(256) void agg_kernel(const unsigned short* __restrict__ h16,
                                                  const float* __restrict__ el,
                                                  const float* __restrict__ er,
                                                  const int* __restrict__ row_start,
                                                  const int* __restrict__ esrc,
                                                  float* __restrict__ out, int N) {
    int wid = threadIdx.x >> 6, lane = threadIdx.x & 63;
    int n = blockIdx.x * 4 + wid;
    if (n >= N) return;
    int j0 = lane * 2;
    int h = lane >> 4;
    int beg = row_start[n], end = row_start[n + 1];
    float erh = er[n * 4 + h];
    float acc0 = 0.f, acc1 = 0.f, den = 0.f;
    for (int i = beg; i < end; i += AGG_U) {
        int s[AGG_U];
        bool ok[AGG_U];
#pragma unroll
        for (int u = 0; u < AGG_U; u++) {
            int idx = i + u;
            ok[u] = idx < end;
            s[u] = esrc[ok[u] ? idx : beg];
        }
        float ev[AGG_U];
        ushort2 v[AGG_U];
#pragma unroll
        for (int u = 0; u < AGG_U; u++) {
            ev[u] = el[s[u] * 4 + h];
            v[u] = *(const ushort2*)(h16 + (size_t)s[u] * HD + j0);
        }
#pragma unroll
        for (int u = 0; u < AGG_U; u++) {
            float e = ev[u] + erh;
            e = (e > 0.f) ? e : NEG_SLOPE * e;
            float ex = ok[u] ? __expf(e) : 0.f;
            den += ex;
            acc0 += ex * bf2f(v[u].x);
            acc1 += ex * bf2f(v[u].y);
        }
    }
    float2 res = *(const float2*)(out + (size_t)n * HD + j0);
    float o0 = res.x, o1 = res.y;
    int indeg = end - beg;
    if (indeg > 0) {
        float sc = sqrtf((float)indeg) / den;  // sqrt(clip(in_deg,1)) / denom
        o0 += sc * acc0;
        o1 += sc * acc1;
    }
    *(float2*)(out + (size_t)n * HD + j0) = make_float2(o0, o1);
}

extern "C" void kernel_launch(void* const* d_in, const int* in_sizes, int n_in,
                              void* d_out, int out_size, void* d_ws, size_t ws_size,
                              hipStream_t stream) {
    const float* feat   = (const float*)d_in[0];
    const int*   src    = (const int*)d_in[1];
    const int*   dst    = (const int*)d_in[2];
    const float* W_fc   = (const float*)d_in[3];
    const float* attn_l = (const float*)d_in[4];
    const float* attn_r = (const float*)d_in[5];
    const float* W_res  = (const float*)d_in[6];
    float* out = (float*)d_out;

    int N = in_sizes[0] / IN_F;   // 50000
    int E = in_sizes[1];          // 800000
    int nb = (N + 255) / 256;     // 196 (<= 256 for scan2)

    size_t off = 0;
    auto alloc = [&](size_t bytes) {
        size_t o = off;
        off = (off + bytes + 255) & ~(size_t)255;
        return o;
    };
    char* ws = (char*)d_ws;
    unsigned short* h16 = (unsigned short*)(ws + alloc((size_t)N * HD * 2));
    __hip_bfloat16* w16 = (__hip_bfloat16*)(ws + alloc((size_t)2 * HD * IN_F * 2));
    float* el           = (float*)(ws + alloc((size_t)N * 4 * 4));
    float* er           = (float*)(ws + alloc((size_t)N * 4 * 4));
    int* out_cnt        = (int*)(ws + alloc((size_t)N * 4));
    int* deg            = (int*)(ws + alloc((size_t)N * 4));
    int* row_start      = (int*)(ws + alloc((size_t)(N + 1) * 4));
    int* bsum           = (int*)(ws + alloc((size_t)nb * 4));
    int* esrc           = (int*)(ws + alloc((size_t)E * 4));

    // runtime-adaptive chunk count: each chunk needs 2 uint16 rows of N
    size_t per_chunk = (size_t)4 * N;
    size_t avail = (ws_size > off + 4096) ? (ws_size - off - 4096) : 0;
    int C = (int)(avail / per_chunk);
    if (C > 128) C = 128;
    if (C < 32) C = 32;           // round-6 footprint proved safe
    unsigned short* pc_dst = (unsigned short*)(ws + alloc((size_t)C * N * 2));
    unsigned short* pc_src = (unsigned short*)(ws + alloc((size_t)C * N * 2));
    int chunk = (E + C - 1) / C;

    int n4each = HD * IN_F / 4;
    cvt_w_kernel<<<(2 * n4each + 255) / 256, 256, 0, stream>>>(
        (const float4*)W_fc, (const float4*)W_res, (ushort4*)w16, n4each);

    hist_kernel<<<dim3(C, 2), 512, 0, stream>>>(src, dst, pc_src, pc_dst, N, E, chunk);
    sum_scan1_kernel<<<nb, 256, 0, stream>>>(pc_src, pc_dst, out_cnt, deg, bsum, N, C);
    scan2_kernel<<<1, 256, 0, stream>>>(bsum, nb, row_start + N, E);
    scan3_kernel<<<nb, 256, 0, stream>>>(deg, bsum, row_start, N);
    place_kernel<<<C, 512, 0, stream>>>(src, dst, pc_dst, row_start, esrc, N, E, chunk);

    gemm_fused<<<(N + 63) / 64, 256, 0, stream>>>(feat, (const __hip_bfloat16*)w16,
                                                  out_cnt, attn_l, attn_r,
                                                  h16, el, er, out, N);

    int nb4 = (N + 3) / 4;
    agg_kernel<<<nb4, 256, 0, stream>>>(h16, el, er, row_start, esrc, out, N);
}

// Round 8
// 157.212 us; speedup vs baseline: 4.0300x; 1.0683x over previous
//
#include <hip/hip_runtime.h>
#include <hip/hip_bf16.h>
#include <math.h>

#define HD 128          // N_HEADS * OUT_FEATS
#define IN_F 256
#define NEG_SLOPE 0.2f
#define NMAX 50000      // problem-fixed node count (LDS histogram capacity)

typedef __attribute__((ext_vector_type(8))) short short8;
typedef __attribute__((ext_vector_type(4))) float f32x4;

__device__ __forceinline__ unsigned short f2bf(float x) {
    __hip_bfloat16 b = __float2bfloat16(x);
    return *(unsigned short*)&b;
}
__device__ __forceinline__ float bf2f(unsigned short u) {
    unsigned int v = ((unsigned int)u) << 16;
    float f;
    __builtin_memcpy(&f, &v, 4);
    return f;
}

// ---------------- weights f32 -> bf16 ----------------
__global__ void cvt_w_kernel(const float4* __restrict__ wfc, const float4* __restrict__ wres,
                             ushort4* __restrict__ w16, int n4each) {
    int idx = blockIdx.x * blockDim.x + threadIdx.x;
    if (idx >= 2 * n4each) return;
    float4 f = (idx < n4each) ? wfc[idx] : wres[idx - n4each];
    ushort4 u;
    u.x = f2bf(f.x); u.y = f2bf(f.y); u.z = f2bf(f.z); u.w = f2bf(f.w);
    w16[idx] = u;
}

// ---------------- per-chunk LDS histogram (uint16-packed, no global atomics) ----
__global__ __launch_bounds__(512) void hist_kernel(const int* __restrict__ src,
                                                   const int* __restrict__ dst,
                                                   unsigned short* __restrict__ pc_src,
                                                   unsigned short* __restrict__ pc_dst,
                                                   int N, int E, int chunk) {
    __shared__ unsigned int h[NMAX / 2];   // 100 KB packed uint16 counts
    int tid = threadIdx.x;
    int nh = N >> 1;                        // N even
    uint4* h4 = (uint4*)h;
    for (int i = tid; i < (nh >> 2); i += 512) h4[i] = make_uint4(0, 0, 0, 0);
    for (int i = (nh & ~3) + tid; i < nh; i += 512) h[i] = 0;
    __syncthreads();

    const int* arr = blockIdx.y ? src : dst;
    int e1 = min(E, (int)(blockIdx.x + 1) * chunk);
    for (int e = blockIdx.x * chunk + tid; e < e1; e += 512) {
        int v = arr[e];
        atomicAdd(&h[v >> 1], 1u << ((v & 1) << 4));
    }
    __syncthreads();

    unsigned short* pc = (blockIdx.y ? pc_src : pc_dst) + (size_t)blockIdx.x * N;
    uint4* pc4 = (uint4*)pc;
    for (int i = tid; i < (nh >> 2); i += 512) pc4[i] = h4[i];
    for (int i = (nh & ~3) + tid; i < nh; i += 512) ((unsigned int*)pc)[i] = h[i];
}

// ---------------- per-node chunk prefix (in place) + degrees + scan1 ----------------
__global__ __launch_bounds__(256) void sum_scan1_kernel(
    const unsigned short* __restrict__ pc_src, unsigned short* __restrict__ pc_dst,
    int* __restrict__ out_cnt, int* __restrict__ deg, int* __restrict__ bsum,
    int N, int C) {
    __shared__ int wsum[4];
    int n = blockIdx.x * 256 + threadIdx.x;
    int sd = 0;
    if (n < N) {
        int ss = 0;
        for (int c = 0; c < C; c++) {
            ss += pc_src[(size_t)c * N + n];
            unsigned short v = pc_dst[(size_t)c * N + n];
            pc_dst[(size_t)c * N + n] = (unsigned short)sd;  // exclusive chunk prefix
            sd += v;
        }
        out_cnt[n] = ss;
        deg[n] = sd;
    }
    int v = (n < N) ? sd : 0;
#pragma unroll
    for (int d = 1; d < 64; d <<= 1) v += __shfl_xor(v, d);
    if ((threadIdx.x & 63) == 0) wsum[threadIdx.x >> 6] = v;
    __syncthreads();
    if (threadIdx.x == 0) bsum[blockIdx.x] = wsum[0] + wsum[1] + wsum[2] + wsum[3];
}

// ---------------- scan of block sums ----------------
__global__ __launch_bounds__(256) void scan2_kernel(int* __restrict__ bsum, int nb,
                                                    int* __restrict__ row_start_N, int E) {
    __shared__ int wtot[4];
    int tid = threadIdx.x, lane = tid & 63, wid = tid >> 6;
    int v = (tid < nb) ? bsum[tid] : 0;
    int incl = v;
#pragma unroll
    for (int d = 1; d < 64; d <<= 1) {
        int t = __shfl_up(incl, d);
        if (lane >= d) incl += t;
    }
    if (lane == 63) wtot[wid] = incl;
    __syncthreads();
    int woff = 0;
    for (int w = 0; w < wid; w++) woff += wtot[w];
    if (tid < nb) bsum[tid] = woff + incl - v;  // exclusive block offset, in place
    if (tid == 0) *row_start_N = E;             // row_start[N]
}

__global__ __launch_bounds__(256) void scan3_kernel(const int* __restrict__ deg,
                                                    const int* __restrict__ boff,
                                                    int* __restrict__ row_start, int N) {
    __shared__ int wsum[4];
    int i = blockIdx.x * 256 + threadIdx.x;
    int lane = threadIdx.x & 63, wid = threadIdx.x >> 6;
    int v = (i < N) ? deg[i] : 0;
    int incl = v;
#pragma unroll
    for (int d = 1; d < 64; d <<= 1) {
        int t = __shfl_up(incl, d);
        if (lane >= d) incl += t;
    }
    if (lane == 63) wsum[wid] = incl;
    __syncthreads();
    int woff = 0;
    for (int w = 0; w < wid; w++) woff += wsum[w];
    int excl = boff[blockIdx.x] + woff + incl - v;
    if (i < N) row_start[i] = excl;
}

// ---------------- placement: LDS cursors seeded from chunk prefix ----------------
__global__ __launch_bounds__(512) void place_kernel(const int* __restrict__ src,
                                                    const int* __restrict__ dst,
                                                    const unsigned short* __restrict__ chunkpre,
                                                    const int* __restrict__ row_start,
                                                    int* __restrict__ esrc,
                                                    int N, int E, int chunk) {
    __shared__ unsigned int cur[NMAX / 2];   // packed uint16 cursors
    int tid = threadIdx.x;
    int nh = N >> 1;
    const unsigned short* cp = chunkpre + (size_t)blockIdx.x * N;
    const uint4* cp4 = (const uint4*)cp;
    uint4* cur4 = (uint4*)cur;
    for (int i = tid; i < (nh >> 2); i += 512) cur4[i] = cp4[i];
    for (int i = (nh & ~3) + tid; i < nh; i += 512) cur[i] = ((const unsigned int*)cp)[i];
    __syncthreads();

    int e1 = min(E, (int)(blockIdx.x + 1) * chunk);
    for (int e = blockIdx.x * chunk + tid; e < e1; e += 512) {
        int d = dst[e], s = src[e];
        int sh = (d & 1) << 4;
        unsigned int old = atomicAdd(&cur[d >> 1], 1u << sh);
        int rank = (old >> sh) & 0xffff;
        esrc[row_start[d] + rank] = s;
    }
}

// ---------------- fused GEMM: cvt(A)->LDS, MFMA, epilogue norm + el/er ----------------
// Block: 32 rows x 256 cols, 4 waves (col panels of 64), 16 KiB LDS.
// cols 0..127 -> h16 (normalized bf16) + el/er; cols 128..255 -> resid into out.
__global__ __launch_bounds__(256) void gemm_fused(
    const float* __restrict__ feat, const __hip_bfloat16* __restrict__ w16,
    const int* __restrict__ out_cnt, const float* __restrict__ attn_l,
    const float* __restrict__ attn_r, unsigned short* __restrict__ h16,
    float* __restrict__ el, float* __restrict__ er, float* __restrict__ out, int N) {
    __shared__ unsigned short sA[32 * 256];  // 16 KiB, XOR-swizzled 16B granules
    int tid = threadIdx.x;
    int lane = tid & 63, wid = tid >> 6;
    int wn = wid;                 // 4 col panels of 64
    int bm = blockIdx.x * 32;
    int l15 = lane & 15, lg = lane >> 4;

    // ---- stage A: f32 -> bf16 into LDS (32 rows x 32 granules) ----
#pragma unroll
    for (int i = 0; i < 4; i++) {
        int G = i * 256 + tid;          // granule id
        int row = G >> 5, gc = G & 31;
        int gm = bm + row;
        gm = (gm < N) ? gm : (N - 1);
        const float4* fp = (const float4*)(feat + (size_t)gm * IN_F + gc * 8);
        float4 f0 = fp[0], f1 = fp[1];
        short8 v;
        v[0] = (short)f2bf(f0.x); v[1] = (short)f2bf(f0.y);
        v[2] = (short)f2bf(f0.z); v[3] = (short)f2bf(f0.w);
        v[4] = (short)f2bf(f1.x); v[5] = (short)f2bf(f1.y);
        v[6] = (short)f2bf(f1.z); v[7] = (short)f2bf(f1.w);
        *(short8*)&sA[row * 256 + ((gc ^ (row & 7)) * 8)] = v;
    }
    __syncthreads();

    int colbase = wn * 64;
    const __hip_bfloat16* bp[4];
#pragma unroll
    for (int ni = 0; ni < 4; ni++) {
        int c = colbase + ni * 16 + l15;  // 0..255
        bp[ni] = w16 + (size_t)c * IN_F + lg * 8;
    }

    f32x4 acc[2][4];
#pragma unroll
    for (int i = 0; i < 2; i++)
#pragma unroll
        for (int j = 0; j < 4; j++) acc[i][j] = (f32x4){0.f, 0.f, 0.f, 0.f};

#pragma unroll
    for (int k0 = 0; k0 < IN_F; k0 += 32) {
        short8 a[2], b[4];
#pragma unroll
        for (int mi = 0; mi < 2; mi++) {
            int row = mi * 16 + l15;
            int gs = ((k0 >> 3) + lg) ^ (row & 7);
            a[mi] = *(const short8*)&sA[row * 256 + gs * 8];
        }
#pragma unroll
        for (int ni = 0; ni < 4; ni++) b[ni] = *(const short8*)(bp[ni] + k0);
#pragma unroll
        for (int mi = 0; mi < 2; mi++)
#pragma unroll
            for (int ni = 0; ni < 4; ni++)
                acc[mi][ni] = __builtin_amdgcn_mfma_f32_16x16x32_bf16(
                    a[mi], b[ni], acc[mi][ni], 0, 0, 0);
    }

    // ---- epilogue. C/D layout: col = lane&15, row = 4*(lane>>4)+reg ----
    bool isH = (wn < 2);
    int colloc = colbase & 127;  // 0 or 64 within each half
    float alv[4], arv[4];
    if (isH) {
#pragma unroll
        for (int ni = 0; ni < 4; ni++) {
            int c = colbase + ni * 16 + l15;  // < 128; flat [H][32] == col index
            alv[ni] = attn_l[c];
            arv[ni] = attn_r[c];
        }
    }
#pragma unroll
    for (int mi = 0; mi < 2; mi++) {
#pragma unroll
        for (int reg = 0; reg < 4; reg++) {
            int r = bm + mi * 16 + lg * 4 + reg;
            bool valid = (r < N);
            int rr = valid ? r : 0;
            if (isH) {
                float nrm = rsqrtf(fmaxf((float)out_cnt[rr], 1.0f));
                float pl0 = 0.f, pl1 = 0.f, pr0 = 0.f, pr1 = 0.f;
#pragma unroll
                for (int ni = 0; ni < 4; ni++) {
                    float v = acc[mi][ni][reg];
                    if (valid)
                        h16[(size_t)r * HD + colloc + ni * 16 + l15] = f2bf(v * nrm);
                    if (ni < 2) { pl0 += v * alv[ni]; pr0 += v * arv[ni]; }
                    else        { pl1 += v * alv[ni]; pr1 += v * arv[ni]; }
                }
                pl0 *= nrm; pl1 *= nrm;  // el uses normalized h; er uses pre-norm h
#pragma unroll
                for (int m = 1; m < 16; m <<= 1) {
                    pl0 += __shfl_xor(pl0, m); pl1 += __shfl_xor(pl1, m);
                    pr0 += __shfl_xor(pr0, m); pr1 += __shfl_xor(pr1, m);
                }
                if (valid && (lane & 15) == 0) {
                    int hb = wn * 2;  // heads hb, hb+1
                    el[r * 4 + hb] = pl0;     el[r * 4 + hb + 1] = pl1;
                    er[r * 4 + hb] = pr0;     er[r * 4 + hb + 1] = pr1;
                }
            } else if (valid) {
#pragma unroll
                for (int ni = 0; ni < 4; ni++)
                    out[(size_t)r * HD + colloc + ni * 16 + l15] = acc[mi][ni][reg];
            }
        }
    }
}

// ---------------- fused edge softmax + weighted scatter + final ----------------
// One wave per dst node, lane-transposed: 64 lanes = 4 edge-slots x 16 dim-lanes.
// Each lane gathers ushort8 (8 dims = 16B); exp computed once per edge-slot;
// cross-slot shfl_xor(16/32) reduce at the end. 8 edges in flight (2 groups).
__global__ __launch_bounds__(256) void agg_kernel(const unsigned short* __restrict__ h16,
                                                  const float* __restrict__ el,
                                                  const float* __restrict__ er,
                                                  const int* __restrict__ row_start,
                                                  const int* __restrict__ esrc,
                                                  float* __restrict__ out, int N) {
    int wid = threadIdx.x >> 6, lane = threadIdx.x & 63;
    int n = blockIdx.x * 4 + wid;
    if (n >= N) return;
    int es = lane >> 4;        // edge slot 0..3
    int l15 = lane & 15;
    int h = l15 >> 2;          // head owning this lane's 8 dims
    int d0 = l15 * 8;
    int beg = row_start[n], end = row_start[n + 1];
    float erh = er[n * 4 + h];
    float den = 0.f;
    float acc[8];
#pragma unroll
    for (int j = 0; j < 8; j++) acc[j] = 0.f;

    for (int i = beg; i < end; i += 8) {
        int idx0 = i + es, idx1 = i + 4 + es;
        bool ok0 = idx0 < end, ok1 = idx1 < end;
        int s0 = esrc[ok0 ? idx0 : beg];
        int s1 = esrc[ok1 ? idx1 : beg];
        float ev0 = el[s0 * 4 + h];
        float ev1 = el[s1 * 4 + h];
        short8 hv0 = *(const short8*)(h16 + (size_t)s0 * HD + d0);
        short8 hv1 = *(const short8*)(h16 + (size_t)s1 * HD + d0);
        float e0 = ev0 + erh; e0 = (e0 > 0.f) ? e0 : NEG_SLOPE * e0;
        float e1 = ev1 + erh; e1 = (e1 > 0.f) ? e1 : NEG_SLOPE * e1;
        float ex0 = ok0 ? __expf(e0) : 0.f;
        float ex1 = ok1 ? __expf(e1) : 0.f;
        den += ex0 + ex1;
#pragma unroll
        for (int j = 0; j < 8; j++)
            acc[j] += ex0 * bf2f((unsigned short)hv0[j]) +
                      ex1 * bf2f((unsigned short)hv1[j]);
    }

    // reduce over the 4 edge slots (lanes differing in bits 4,5)
#pragma unroll
    for (int m = 16; m < 64; m <<= 1) {
        den += __shfl_xor(den, m);
#pragma unroll
        for (int j = 0; j < 8; j++) acc[j] += __shfl_xor(acc[j], m);
    }

    if (es == 0) {
        float* op = out + (size_t)n * HD + d0;
        float4 r0 = *(const float4*)op;
        float4 r1 = *(const float4*)(op + 4);
        int indeg = end - beg;
        float sc = (indeg > 0) ? sqrtf((float)indeg) / den : 0.f;
        r0.x += sc * acc[0]; r0.y += sc * acc[1];
        r0.z += sc * acc[2]; r0.w += sc * acc[3];
        r1.x += sc * acc[4]; r1.y += sc * acc[5];
        r1.z += sc * acc[6]; r1.w += sc * acc[7];
        *(float4*)op = r0;
        *(float4*)(op + 4) = r1;
    }
}

extern "C" void kernel_launch(void* const* d_in, const int* in_sizes, int n_in,
                              void* d_out, int out_size, void* d_ws, size_t ws_size,
                              hipStream_t stream) {
    const float* feat   = (const float*)d_in[0];
    const int*   src    = (const int*)d_in[1];
    const int*   dst    = (const int*)d_in[2];
    const float* W_fc   = (const float*)d_in[3];
    const float* attn_l = (const float*)d_in[4];
    const float* attn_r = (const float*)d_in[5];
    const float* W_res  = (const float*)d_in[6];
    float* out = (float*)d_out;

    int N = in_sizes[0] / IN_F;   // 50000
    int E = in_sizes[1];          // 800000
    int nb = (N + 255) / 256;     // 196 (<= 256 for scan2)

    size_t off = 0;
    auto alloc = [&](size_t bytes) {
        size_t o = off;
        off = (off + bytes + 255) & ~(size_t)255;
        return o;
    };
    char* ws = (char*)d_ws;
    unsigned short* h16 = (unsigned short*)(ws + alloc((size_t)N * HD * 2));
    __hip_bfloat16* w16 = (__hip_bfloat16*)(ws + alloc((size_t)2 * HD * IN_F * 2));
    float* el           = (float*)(ws + alloc((size_t)N * 4 * 4));
    float* er           = (float*)(ws + alloc((size_t)N * 4 * 4));
    int* out_cnt        = (int*)(ws + alloc((size_t)N * 4));
    int* deg            = (int*)(ws + alloc((size_t)N * 4));
    int* row_start      = (int*)(ws + alloc((size_t)(N + 1) * 4));
    int* bsum           = (int*)(ws + alloc((size_t)nb * 4));
    int* esrc           = (int*)(ws + alloc((size_t)E * 4));

    // runtime-adaptive chunk count: each chunk needs 2 uint16 rows of N
    size_t per_chunk = (size_t)4 * N;
    size_t avail = (ws_size > off + 4096) ? (ws_size - off - 4096) : 0;
    int C = (int)(avail / per_chunk);
    if (C > 128) C = 128;
    if (C < 32) C = 32;           // round-6 footprint proved safe
    unsigned short* pc_dst = (unsigned short*)(ws + alloc((size_t)C * N * 2));
    unsigned short* pc_src = (unsigned short*)(ws + alloc((size_t)C * N * 2));
    int chunk = (E + C - 1) / C;

    int n4each = HD * IN_F / 4;
    cvt_w_kernel<<<(2 * n4each + 255) / 256, 256, 0, stream>>>(
        (const float4*)W_fc, (const float4*)W_res, (ushort4*)w16, n4each);

    hist_kernel<<<dim3(C, 2), 512, 0, stream>>>(src, dst, pc_src, pc_dst, N, E, chunk);
    sum_scan1_kernel<<<nb, 256, 0, stream>>>(pc_src, pc_dst, out_cnt, deg, bsum, N, C);
    scan2_kernel<<<1, 256, 0, stream>>>(bsum, nb, row_start + N, E);
    scan3_kernel<<<nb, 256, 0, stream>>>(deg, bsum, row_start, N);
    place_kernel<<<C, 512, 0, stream>>>(src, dst, pc_dst, row_start, esrc, N, E, chunk);

    gemm_fused<<<(N + 31) / 32, 256, 0, stream>>>(feat, (const __hip_bfloat16*)w16,
                                                  out_cnt, attn_l, attn_r,
                                                  h16, el, er, out, N);

    int nb4 = (N + 3) / 4;
    agg_kernel<<<nb4, 256, 0, stream>>>(h16, el, er, row_start, esrc, out, N);
}

// Round 9
// 149.070 us; speedup vs baseline: 4.2501x; 1.0546x over previous
//
#include <hip/hip_runtime.h>
#include <hip/hip_bf16.h>
#include <math.h>

#define HD 128          // N_HEADS * OUT_FEATS
#define IN_F 256
#define NEG_SLOPE 0.2f
#define NMAX 50000      // problem-fixed node count (LDS histogram capacity)
#define GEMM_BLOCKS 512 // persistent gemm grid (2 blocks/CU)

typedef __attribute__((ext_vector_type(8))) short short8;
typedef __attribute__((ext_vector_type(4))) float f32x4;

__device__ __forceinline__ unsigned short f2bf(float x) {
    __hip_bfloat16 b = __float2bfloat16(x);
    return *(unsigned short*)&b;
}
__device__ __forceinline__ float bf2f(unsigned short u) {
    unsigned int v = ((unsigned int)u) << 16;
    float f;
    __builtin_memcpy(&f, &v, 4);
    return f;
}

// ---------------- weights f32 -> bf16 ----------------
__global__ void cvt_w_kernel(const float4* __restrict__ wfc, const float4* __restrict__ wres,
                             ushort4* __restrict__ w16, int n4each) {
    int idx = blockIdx.x * blockDim.x + threadIdx.x;
    if (idx >= 2 * n4each) return;
    float4 f = (idx < n4each) ? wfc[idx] : wres[idx - n4each];
    ushort4 u;
    u.x = f2bf(f.x); u.y = f2bf(f.y); u.z = f2bf(f.z); u.w = f2bf(f.w);
    w16[idx] = u;
}

// ---------------- per-chunk LDS histogram (uint16-packed, no global atomics) ----
__global__ __launch_bounds__(512) void hist_kernel(const int* __restrict__ src,
                                                   const int* __restrict__ dst,
                                                   unsigned short* __restrict__ pc_src,
                                                   unsigned short* __restrict__ pc_dst,
                                                   int N, int E, int chunk) {
    __shared__ unsigned int h[NMAX / 2];   // 100 KB packed uint16 counts
    int tid = threadIdx.x;
    int nh = N >> 1;                        // N even
    uint4* h4 = (uint4*)h;
    for (int i = tid; i < (nh >> 2); i += 512) h4[i] = make_uint4(0, 0, 0, 0);
    for (int i = (nh & ~3) + tid; i < nh; i += 512) h[i] = 0;
    __syncthreads();

    const int* arr = blockIdx.y ? src : dst;
    int e1 = min(E, (int)(blockIdx.x + 1) * chunk);
    for (int e = blockIdx.x * chunk + tid; e < e1; e += 512) {
        int v = arr[e];
        atomicAdd(&h[v >> 1], 1u << ((v & 1) << 4));
    }
    __syncthreads();

    unsigned short* pc = (blockIdx.y ? pc_src : pc_dst) + (size_t)blockIdx.x * N;
    uint4* pc4 = (uint4*)pc;
    for (int i = tid; i < (nh >> 2); i += 512) pc4[i] = h4[i];
    for (int i = (nh & ~3) + tid; i < nh; i += 512) ((unsigned int*)pc)[i] = h[i];
}

// ---------------- per-node chunk prefix (in place) + degrees + scan1 ----------------
__global__ __launch_bounds__(256) void sum_scan1_kernel(
    const unsigned short* __restrict__ pc_src, unsigned short* __restrict__ pc_dst,
    int* __restrict__ out_cnt, int* __restrict__ deg, int* __restrict__ bsum,
    int N, int C) {
    __shared__ int wsum[4];
    int n = blockIdx.x * 256 + threadIdx.x;
    int sd = 0;
    if (n < N) {
        int ss = 0;
        for (int c = 0; c < C; c++) {
            ss += pc_src[(size_t)c * N + n];
            unsigned short v = pc_dst[(size_t)c * N + n];
            pc_dst[(size_t)c * N + n] = (unsigned short)sd;  // exclusive chunk prefix
            sd += v;
        }
        out_cnt[n] = ss;
        deg[n] = sd;
    }
    int v = (n < N) ? sd : 0;
#pragma unroll
    for (int d = 1; d < 64; d <<= 1) v += __shfl_xor(v, d);
    if ((threadIdx.x & 63) == 0) wsum[threadIdx.x >> 6] = v;
    __syncthreads();
    if (threadIdx.x == 0) bsum[blockIdx.x] = wsum[0] + wsum[1] + wsum[2] + wsum[3];
}

// ---------------- scan of block sums ----------------
__global__ __launch_bounds__(256) void scan2_kernel(int* __restrict__ bsum, int nb,
                                                    int* __restrict__ row_start_N, int E) {
    __shared__ int wtot[4];
    int tid = threadIdx.x, lane = tid & 63, wid = tid >> 6;
    int v = (tid < nb) ? bsum[tid] : 0;
    int incl = v;
#pragma unroll
    for (int d = 1; d < 64; d <<= 1) {
        int t = __shfl_up(incl, d);
        if (lane >= d) incl += t;
    }
    if (lane == 63) wtot[wid] = incl;
    __syncthreads();
    int woff = 0;
    for (int w = 0; w < wid; w++) woff += wtot[w];
    if (tid < nb) bsum[tid] = woff + incl - v;  // exclusive block offset, in place
    if (tid == 0) *row_start_N = E;             // row_start[N]
}

__global__ __launch_bounds__(256) void scan3_kernel(const int* __restrict__ deg,
                                                    const int* __restrict__ boff,
                                                    int* __restrict__ row_start, int N) {
    __shared__ int wsum[4];
    int i = blockIdx.x * 256 + threadIdx.x;
    int lane = threadIdx.x & 63, wid = threadIdx.x >> 6;
    int v = (i < N) ? deg[i] : 0;
    int incl = v;
#pragma unroll
    for (int d = 1; d < 64; d <<= 1) {
        int t = __shfl_up(incl, d);
        if (lane >= d) incl += t;
    }
    if (lane == 63) wsum[wid] = incl;
    __syncthreads();
    int woff = 0;
    for (int w = 0; w < wid; w++) woff += wsum[w];
    int excl = boff[blockIdx.x] + woff + incl - v;
    if (i < N) row_start[i] = excl;
}

// ---------------- placement: LDS cursors seeded from chunk prefix ----------------
__global__ __launch_bounds__(512) void place_kernel(const int* __restrict__ src,
                                                    const int* __restrict__ dst,
                                                    const unsigned short* __restrict__ chunkpre,
                                                    const int* __restrict__ row_start,
                                                    int* __restrict__ esrc,
                                                    int N, int E, int chunk) {
    __shared__ unsigned int cur[NMAX / 2];   // packed uint16 cursors
    int tid = threadIdx.x;
    int nh = N >> 1;
    const unsigned short* cp = chunkpre + (size_t)blockIdx.x * N;
    const uint4* cp4 = (const uint4*)cp;
    uint4* cur4 = (uint4*)cur;
    for (int i = tid; i < (nh >> 2); i += 512) cur4[i] = cp4[i];
    for (int i = (nh & ~3) + tid; i < nh; i += 512) cur[i] = ((const unsigned int*)cp)[i];
    __syncthreads();

    int e1 = min(E, (int)(blockIdx.x + 1) * chunk);
    for (int e = blockIdx.x * chunk + tid; e < e1; e += 512) {
        int d = dst[e], s = src[e];
        int sh = (d & 1) << 4;
        unsigned int old = atomicAdd(&cur[d >> 1], 1u << sh);
        int rank = (old >> sh) & 0xffff;
        esrc[row_start[d] + rank] = s;
    }
}

// ---------------- persistent fused GEMM: B in regs, dbuf LDS A-stage ----------------
// 512 blocks x 4 waves; wave wn owns cols wn*64..+63 for ALL row tiles.
// B panel (64 cols x 256 K) lives in 32 short8 regs per lane for the whole kernel.
// Per 32-row tile: global f32 -> regs -> cvt -> LDS(buf) -> MFMA; next tile's
// loads issued before the barrier so HBM latency hides under compute.
__global__ __launch_bounds__(256, 2) void gemm_fused(
    const float* __restrict__ feat, const __hip_bfloat16* __restrict__ w16,
    const int* __restrict__ out_cnt, const float* __restrict__ attn_l,
    const float* __restrict__ attn_r, unsigned short* __restrict__ h16,
    float* __restrict__ el, float* __restrict__ er, float* __restrict__ out,
    int N, int ntiles) {
    __shared__ unsigned short sA[2][32 * 256];  // 2 x 16 KiB, XOR-swizzled granules
    int tid = threadIdx.x;
    int lane = tid & 63, wn = tid >> 6;
    int l15 = lane & 15, lg = lane >> 4;
    int colbase = wn * 64;

    // ---- B panel preload: 4 col-frags x 8 k-steps, held in regs ----
    short8 breg[4][8];
#pragma unroll
    for (int ni = 0; ni < 4; ni++) {
        const __hip_bfloat16* bp = w16 + (size_t)(colbase + ni * 16 + l15) * IN_F + lg * 8;
#pragma unroll
        for (int kk = 0; kk < 8; kk++)
            breg[ni][kk] = *(const short8*)(bp + kk * 32);
    }

    bool isH = (wn < 2);
    int colloc = colbase & 127;
    float alv[4], arv[4];
    if (isH) {
#pragma unroll
        for (int ni = 0; ni < 4; ni++) {
            int c = colbase + ni * 16 + l15;   // < 128; flat [H][32] == col index
            alv[ni] = attn_l[c];
            arv[ni] = attn_r[c];
        }
    }

    // stage-load thread mapping: granule G = i*256+tid -> row G>>5, gcol G&31
    int srow[4], sgc[4];
#pragma unroll
    for (int i = 0; i < 4; i++) {
        int G = i * 256 + tid;
        srow[i] = G >> 5;
        sgc[i] = G & 31;
    }

    float4 fA[4][2];
    int t = blockIdx.x;
    // prefetch first tile
#pragma unroll
    for (int i = 0; i < 4; i++) {
        int gm = t * 32 + srow[i];
        gm = (gm < N) ? gm : (N - 1);
        const float4* fp = (const float4*)(feat + (size_t)gm * IN_F + sgc[i] * 8);
        fA[i][0] = fp[0];
        fA[i][1] = fp[1];
    }

    int cur = 0;
    for (; t < ntiles; t += GEMM_BLOCKS) {
        // ---- convert staged regs -> LDS buf[cur] ----
#pragma unroll
        for (int i = 0; i < 4; i++) {
            short8 v;
            v[0] = (short)f2bf(fA[i][0].x); v[1] = (short)f2bf(fA[i][0].y);
            v[2] = (short)f2bf(fA[i][0].z); v[3] = (short)f2bf(fA[i][0].w);
            v[4] = (short)f2bf(fA[i][1].x); v[5] = (short)f2bf(fA[i][1].y);
            v[6] = (short)f2bf(fA[i][1].z); v[7] = (short)f2bf(fA[i][1].w);
            *(short8*)&sA[cur][srow[i] * 256 + ((sgc[i] ^ (srow[i] & 7)) * 8)] = v;
        }
        // ---- issue next tile's loads (latency hides under compute below) ----
        int tn = t + GEMM_BLOCKS;
        if (tn < ntiles) {
#pragma unroll
            for (int i = 0; i < 4; i++) {
                int gm = tn * 32 + srow[i];
                gm = (gm < N) ? gm : (N - 1);
                const float4* fp = (const float4*)(feat + (size_t)gm * IN_F + sgc[i] * 8);
                fA[i][0] = fp[0];
                fA[i][1] = fp[1];
            }
        }
        __syncthreads();

        // ---- k-loop: pure ds_read + MFMA ----
        f32x4 acc[2][4];
#pragma unroll
        for (int i = 0; i < 2; i++)
#pragma unroll
            for (int j = 0; j < 4; j++) acc[i][j] = (f32x4){0.f, 0.f, 0.f, 0.f};
#pragma unroll
        for (int kk = 0; kk < 8; kk++) {
            short8 a[2];
#pragma unroll
            for (int mi = 0; mi < 2; mi++) {
                int row = mi * 16 + l15;
                int gs = (kk * 4 + lg) ^ (row & 7);
                a[mi] = *(const short8*)&sA[cur][row * 256 + gs * 8];
            }
#pragma unroll
            for (int mi = 0; mi < 2; mi++)
#pragma unroll
                for (int ni = 0; ni < 4; ni++)
                    acc[mi][ni] = __builtin_amdgcn_mfma_f32_16x16x32_bf16(
                        a[mi], breg[ni][kk], acc[mi][ni], 0, 0, 0);
        }

        // ---- epilogue. C/D layout: col = lane&15, row = 4*(lane>>4)+reg ----
        int bm = t * 32;
#pragma unroll
        for (int mi = 0; mi < 2; mi++) {
#pragma unroll
            for (int reg = 0; reg < 4; reg++) {
                int r = bm + mi * 16 + lg * 4 + reg;
                bool valid = (r < N);
                int rr = valid ? r : 0;
                if (isH) {
                    float nrm = rsqrtf(fmaxf((float)out_cnt[rr], 1.0f));
                    float pl0 = 0.f, pl1 = 0.f, pr0 = 0.f, pr1 = 0.f;
#pragma unroll
                    for (int ni = 0; ni < 4; ni++) {
                        float v = acc[mi][ni][reg];
                        if (valid)
                            h16[(size_t)r * HD + colloc + ni * 16 + l15] = f2bf(v * nrm);
                        if (ni < 2) { pl0 += v * alv[ni]; pr0 += v * arv[ni]; }
                        else        { pl1 += v * alv[ni]; pr1 += v * arv[ni]; }
                    }
                    pl0 *= nrm; pl1 *= nrm;  // el normalized; er pre-norm
#pragma unroll
                    for (int m = 1; m < 16; m <<= 1) {
                        pl0 += __shfl_xor(pl0, m); pl1 += __shfl_xor(pl1, m);
                        pr0 += __shfl_xor(pr0, m); pr1 += __shfl_xor(pr1, m);
                    }
                    if (valid && (lane & 15) == 0) {
                        int hb = wn * 2;  // heads hb, hb+1
                        el[r * 4 + hb] = pl0;     el[r * 4 + hb + 1] = pl1;
                        er[r * 4 + hb] = pr0;     er[r * 4 + hb + 1] = pr1;
                    }
                } else if (valid) {
#pragma unroll
                    for (int ni = 0; ni < 4; ni++)
                        out[(size_t)r * HD + colloc + ni * 16 + l15] = acc[mi][ni][reg];
                }
            }
        }
        cur ^= 1;
    }
}

// ---------------- fused edge softmax + weighted scatter + final ----------------
// One wave per dst node, lane-transposed: 64 lanes = 4 edge-slots x 16 dim-lanes.
__global__ __launch_bounds__(256) void agg_kernel(const unsigned short* __restrict__ h16,
                                                  const float* __restrict__ el,
                                                  const float* __restrict__ er,
                                                  const int* __restrict__ row_start,
                                                  const int* __restrict__ esrc,
                                                  float* __restrict__ out, int N) {
    int wid = threadIdx.x >> 6, lane = threadIdx.x & 63;
    int n = blockIdx.x * 4 + wid;
    if (n >= N) return;
    int es = lane >> 4;        // edge slot 0..3
    int l15 = lane & 15;
    int h = l15 >> 2;          // head owning this lane's 8 dims
    int d0 = l15 * 8;
    int beg = row_start[n], end = row_start[n + 1];
    float erh = er[n * 4 + h];
    float den = 0.f;
    float acc[8];
#pragma unroll
    for (int j = 0; j < 8; j++) acc[j] = 0.f;

    for (int i = beg; i < end; i += 8) {
        int idx0 = i + es, idx1 = i + 4 + es;
        bool ok0 = idx0 < end, ok1 = idx1 < end;
        int s0 = esrc[ok0 ? idx0 : beg];
        int s1 = esrc[ok1 ? idx1 : beg];
        float ev0 = el[s0 * 4 + h];
        float ev1 = el[s1 * 4 + h];
        short8 hv0 = *(const short8*)(h16 + (size_t)s0 * HD + d0);
        short8 hv1 = *(const short8*)(h16 + (size_t)s1 * HD + d0);
        float e0 = ev0 + erh; e0 = (e0 > 0.f) ? e0 : NEG_SLOPE * e0;
        float e1 = ev1 + erh; e1 = (e1 > 0.f) ? e1 : NEG_SLOPE * e1;
        float ex0 = ok0 ? __expf(e0) : 0.f;
        float ex1 = ok1 ? __expf(e1) : 0.f;
        den += ex0 + ex1;
#pragma unroll
        for (int j = 0; j < 8; j++)
            acc[j] += ex0 * bf2f((unsigned short)hv0[j]) +
                      ex1 * bf2f((unsigned short)hv1[j]);
    }

#pragma unroll
    for (int m = 16; m < 64; m <<= 1) {
        den += __shfl_xor(den, m);
#pragma unroll
        for (int j = 0; j < 8; j++) acc[j] += __shfl_xor(acc[j], m);
    }

    if (es == 0) {
        float* op = out + (size_t)n * HD + d0;
        float4 r0 = *(const float4*)op;
        float4 r1 = *(const float4*)(op + 4);
        int indeg = end - beg;
        float sc = (indeg > 0) ? sqrtf((float)indeg) / den : 0.f;
        r0.x += sc * acc[0]; r0.y += sc * acc[1];
        r0.z += sc * acc[2]; r0.w += sc * acc[3];
        r1.x += sc * acc[4]; r1.y += sc * acc[5];
        r1.z += sc * acc[6]; r1.w += sc * acc[7];
        *(float4*)op = r0;
        *(float4*)(op + 4) = r1;
    }
}

extern "C" void kernel_launch(void* const* d_in, const int* in_sizes, int n_in,
                              void* d_out, int out_size, void* d_ws, size_t ws_size,
                              hipStream_t stream) {
    const float* feat   = (const float*)d_in[0];
    const int*   src    = (const int*)d_in[1];
    const int*   dst    = (const int*)d_in[2];
    const float* W_fc   = (const float*)d_in[3];
    const float* attn_l = (const float*)d_in[4];
    const float* attn_r = (const float*)d_in[5];
    const float* W_res  = (const float*)d_in[6];
    float* out = (float*)d_out;

    int N = in_sizes[0] / IN_F;   // 50000
    int E = in_sizes[1];          // 800000
    int nb = (N + 255) / 256;     // 196 (<= 256 for scan2)

    size_t off = 0;
    auto alloc = [&](size_t bytes) {
        size_t o = off;
        off = (off + bytes + 255) & ~(size_t)255;
        return o;
    };
    char* ws = (char*)d_ws;
    unsigned short* h16 = (unsigned short*)(ws + alloc((size_t)N * HD * 2));
    __hip_bfloat16* w16 = (__hip_bfloat16*)(ws + alloc((size_t)2 * HD * IN_F * 2));
    float* el           = (float*)(ws + alloc((size_t)N * 4 * 4));
    float* er           = (float*)(ws + alloc((size_t)N * 4 * 4));
    int* out_cnt        = (int*)(ws + alloc((size_t)N * 4));
    int* deg            = (int*)(ws + alloc((size_t)N * 4));
    int* row_start      = (int*)(ws + alloc((size_t)(N + 1) * 4));
    int* bsum           = (int*)(ws + alloc((size_t)nb * 4));
    int* esrc           = (int*)(ws + alloc((size_t)E * 4));

    // runtime-adaptive chunk count: each chunk needs 2 uint16 rows of N
    size_t per_chunk = (size_t)4 * N;
    size_t avail = (ws_size > off + 4096) ? (ws_size - off - 4096) : 0;
    int C = (int)(avail / per_chunk);
    if (C > 128) C = 128;
    if (C < 32) C = 32;           // round-6 footprint proved safe
    unsigned short* pc_dst = (unsigned short*)(ws + alloc((size_t)C * N * 2));
    unsigned short* pc_src = (unsigned short*)(ws + alloc((size_t)C * N * 2));
    int chunk = (E + C - 1) / C;

    int n4each = HD * IN_F / 4;
    cvt_w_kernel<<<(2 * n4each + 255) / 256, 256, 0, stream>>>(
        (const float4*)W_fc, (const float4*)W_res, (ushort4*)w16, n4each);

    hist_kernel<<<dim3(C, 2), 512, 0, stream>>>(src, dst, pc_src, pc_dst, N, E, chunk);
    sum_scan1_kernel<<<nb, 256, 0, stream>>>(pc_src, pc_dst, out_cnt, deg, bsum, N, C);
    scan2_kernel<<<1, 256, 0, stream>>>(bsum, nb, row_start + N, E);
    scan3_kernel<<<nb, 256, 0, stream>>>(deg, bsum, row_start, N);
    place_kernel<<<C, 512, 0, stream>>>(src, dst, pc_dst, row_start, esrc, N, E, chunk);

    int ntiles = (N + 31) / 32;
    gemm_fused<<<GEMM_BLOCKS, 256, 0, stream>>>(feat, (const __hip_bfloat16*)w16,
                                                out_cnt, attn_l, attn_r,
                                                h16, el, er, out, N, ntiles);

    int nb4 = (N + 3) / 4;
    agg_kernel<<<nb4, 256, 0, stream>>>(h16, el, er, row_start, esrc, out, N);
}